// Round 15
// baseline (136.034 us; speedup 1.0000x reference)
//
#include <hip/hip_runtime.h>
#include <hip/hip_bf16.h>
#include <math.h>

#define NHEADS 16
#define HDIM   64
#define BATCH  2
#define SEQLEN 2048
#define DIMSZ  1024

typedef _Float16 f16x8 __attribute__((ext_vector_type(8)));
typedef float    f32x4 __attribute__((ext_vector_type(4)));
typedef unsigned short u16x8 __attribute__((ext_vector_type(8)));
typedef unsigned int   u32x4 __attribute__((ext_vector_type(4)));

__device__ __forceinline__ float rope_theta(int c) {
    int i = c & 31;
    return (float)pow(10000.0, -(double)i / 32.0);
}
__device__ __forceinline__ unsigned short f16u(float f) {
    _Float16 h = (_Float16)f;
    return *reinterpret_cast<unsigned short*>(&h);
}
__device__ __forceinline__ void async_copy16(const void* gsrc, void* lds) {
    __builtin_amdgcn_global_load_lds(
        (const __attribute__((address_space(1))) unsigned int*)gsrc,
        (__attribute__((address_space(3))) unsigned int*)lds, 16, 0, 0);
}

// ---------------------------------------------------------------------------
// prep: f32->f16 conversions (x, Wq|Wk|Wv concat, Wo), bias concat, rope tables
// ---------------------------------------------------------------------------
__global__ __launch_bounds__(256) void prep_kernel(
    const float* __restrict__ x, const float* __restrict__ Wq,
    const float* __restrict__ Wk, const float* __restrict__ Wv,
    const float* __restrict__ Wo, const float* __restrict__ bq,
    const float* __restrict__ bk, const float* __restrict__ bv,
    unsigned short* __restrict__ x16, unsigned short* __restrict__ Wqkv16,
    unsigned short* __restrict__ Wo16, float* __restrict__ biasqkv,
    float* __restrict__ ropeC, float* __restrict__ ropeS)
{
    const int NV = (4194304 + 4 * 1048576) / 8;   // 1,048,576 vec8 chunks
    int gid = blockIdx.x * 256 + threadIdx.x;
    for (int i = gid; i < NV; i += gridDim.x * 256) {
        long e = (long)i * 8;
        const float* src; unsigned short* dst; long off;
        if (e < 4194304)      { src = x;  dst = x16;              off = e; }
        else if (e < 5242880) { src = Wq; dst = Wqkv16;           off = e - 4194304; }
        else if (e < 6291456) { src = Wk; dst = Wqkv16 + 1048576; off = e - 5242880; }
        else if (e < 7340032) { src = Wv; dst = Wqkv16 + 2097152; off = e - 6291456; }
        else                  { src = Wo; dst = Wo16;             off = e - 7340032; }
        float4 v0 = *reinterpret_cast<const float4*>(src + off);
        float4 v1 = *reinterpret_cast<const float4*>(src + off + 4);
        u16x8 o;
        o[0] = f16u(v0.x); o[1] = f16u(v0.y); o[2] = f16u(v0.z); o[3] = f16u(v0.w);
        o[4] = f16u(v1.x); o[5] = f16u(v1.y); o[6] = f16u(v1.z); o[7] = f16u(v1.w);
        *reinterpret_cast<u16x8*>(dst + off) = o;
    }
    if (gid < 65536) {
        int npos = gid >> 5, j = gid & 31;
        float f = (float)npos * rope_theta(j);
        ropeC[gid] = cosf(f);
        ropeS[gid] = sinf(f);
    }
    if (gid < 3072) {
        biasqkv[gid] = gid < 1024 ? bq[gid] : (gid < 2048 ? bk[gid - 1024] : bv[gid - 2048]);
    }
}

// ---------------------------------------------------------------------------
// Fused QKV GEMM + bias + (non-standard) rope. 512 thr / 8 waves (64x32
// sub-tiles), double-buffered swizzled LDS, 1 barrier per K-step.
// ---------------------------------------------------------------------------
__global__ __launch_bounds__(512, 4) void qkv_gemm_kernel(
    const unsigned short* __restrict__ A, const unsigned short* __restrict__ B,
    const float* __restrict__ bias, const float* __restrict__ ropeC,
    const float* __restrict__ ropeS, unsigned short* __restrict__ QKV)
{
    __shared__ __align__(16) unsigned char smem[65536];
    const int tid = threadIdx.x;
    const int w = tid >> 6, l = tid & 63;
    const int g = l >> 4, lx = l & 15;
    const int wr = w >> 2, wc = w & 3;        // 2x4 wave grid: 64x32 subtile
    const int row0 = blockIdx.y * 128;
    const int col0 = blockIdx.x * 128;
    const unsigned short* Ab = A + (size_t)row0 * DIMSZ;
    const unsigned short* Bb = B + (size_t)col0 * DIMSZ;

    const int sr = tid >> 3;                   // 0..63
    const int sc = tid & 7;
    const int ssw = sc ^ (sr & 7);
    const size_t sAoff0 = (size_t)sr * DIMSZ + ssw * 8;
    const size_t sAoff1 = (size_t)(64 + sr) * DIMSZ + ssw * 8;

    f32x4 acc[4][2] = {};
    async_copy16(Ab + sAoff0, smem + tid * 16);
    async_copy16(Ab + sAoff1, smem + 8192 + tid * 16);
    async_copy16(Bb + sAoff0, smem + 16384 + tid * 16);
    async_copy16(Bb + sAoff1, smem + 16384 + 8192 + tid * 16);
    __syncthreads();

    int buf = 0;
    for (int k0 = 0; k0 < DIMSZ; k0 += 64) {
        if (k0 + 64 < DIMSZ) {
            const int nb = (buf ^ 1) * 32768;
            async_copy16(Ab + sAoff0 + k0 + 64, smem + nb + tid * 16);
            async_copy16(Ab + sAoff1 + k0 + 64, smem + nb + 8192 + tid * 16);
            async_copy16(Bb + sAoff0 + k0 + 64, smem + nb + 16384 + tid * 16);
            async_copy16(Bb + sAoff1 + k0 + 64, smem + nb + 16384 + 8192 + tid * 16);
        }
        const int ab = buf * 32768, bb2 = ab + 16384;
        #pragma unroll
        for (int ks = 0; ks < 2; ++ks) {
            f16x8 af[4], bf[2];
            #pragma unroll
            for (int m = 0; m < 4; ++m) {
                int r = wr * 64 + m * 16 + lx;
                af[m] = *reinterpret_cast<const f16x8*>(
                    &smem[ab + r * 128 + ((ks * 64 + g * 16) ^ ((r & 7) << 4))]);
            }
            #pragma unroll
            for (int n = 0; n < 2; ++n) {
                int r = wc * 32 + n * 16 + lx;
                bf[n] = *reinterpret_cast<const f16x8*>(
                    &smem[bb2 + r * 128 + ((ks * 64 + g * 16) ^ ((r & 7) << 4))]);
            }
            #pragma unroll
            for (int m = 0; m < 4; ++m)
                #pragma unroll
                for (int n = 0; n < 2; ++n)
                    acc[m][n] = __builtin_amdgcn_mfma_f32_16x16x32_f16(af[m], bf[n], acc[m][n], 0, 0, 0);
        }
        __syncthreads();
        buf ^= 1;
    }

    const int proj = col0 >> 10;               // block-uniform
    const int cin128 = (col0 & 1023);
    float bsv[2];
    #pragma unroll
    for (int n = 0; n < 2; ++n) bsv[n] = bias[col0 + wc * 32 + n * 16 + lx];

    if (proj == 2) {
        _Float16* T = (_Float16*)smem;   // [128][136]
        #pragma unroll
        for (int m = 0; m < 4; ++m) {
            int rl0 = wr * 64 + m * 16 + g * 4;
            #pragma unroll
            for (int r2 = 0; r2 < 4; ++r2) {
                int rlocal = rl0 + r2;
                int npos = (row0 + rlocal) & (SEQLEN - 1);
                const float* rcp = ropeC + npos * 32;
                const float* rsp = ropeS + npos * 32;
                #pragma unroll
                for (int n = 0; n < 2; ++n) {
                    float v = acc[m][n][r2] + bsv[n];
                    float o = __shfl_xor(v, 1);
                    int dcol = wc * 32 + n * 16 + lx;
                    int c = dcol & 63;
                    const float* tab = (c < 32) ? rcp : rsp;
                    float Rd = tab[c & 31];
                    float Rp = tab[(c & 31) ^ 1];
                    float y; int outc;
                    if (c & 1) { y = o * Rd + v * Rp; outc = (c >> 1) + 32; }
                    else       { y = v * Rd - o * Rp; outc = c >> 1; }
                    T[((dcol >> 6) * 64 + outc) * 136 + rlocal] = (_Float16)y;
                }
            }
        }
        __syncthreads();
        int b = row0 >> 11, npos0 = row0 & (SEQLEN - 1);
        int hd0 = cin128 >> 6;
        int trow = tid >> 2;
        int cbase = (tid & 3) * 32;
        int head = hd0 + (trow >> 6);
        int outd = trow & 63;
        unsigned short* vdst = QKV + 8388608 +
            (((size_t)b * NHEADS + head) * HDIM + outd) * SEQLEN + npos0 + cbase;
        #pragma unroll
        for (int i2 = 0; i2 < 4; ++i2) {
            f16x8 val = *reinterpret_cast<const f16x8*>(&T[trow * 136 + cbase + i2 * 8]);
            *reinterpret_cast<f16x8*>(vdst + i2 * 8) = val;
        }
    } else {
        #pragma unroll
        for (int m = 0; m < 4; ++m) {
            int rbase = row0 + wr * 64 + m * 16 + g * 4;
            #pragma unroll
            for (int r2 = 0; r2 < 4; ++r2) {
                int rglob = rbase + r2;
                int b = rglob >> 11, npos = rglob & (SEQLEN - 1);
                const float* rcp = ropeC + npos * 32;
                const float* rsp = ropeS + npos * 32;
                #pragma unroll
                for (int n = 0; n < 2; ++n) {
                    float v = acc[m][n][r2] + bsv[n];
                    float o = __shfl_xor(v, 1);
                    int hd = (cin128 + wc * 32 + n * 16) >> 6;
                    int c = ((wc * 32 + n * 16) & 63) + lx;
                    const float* tab = (c < 32) ? rcp : rsp;
                    float Rd = tab[c & 31];
                    float Rp = tab[(c & 31) ^ 1];
                    float y; int outc;
                    if (c & 1) { y = o * Rd + v * Rp; outc = (c >> 1) + 32; }
                    else       { y = v * Rd - o * Rp; outc = c >> 1; }
                    unsigned short* Orow = QKV +
                        ((((size_t)proj * BATCH + b) * NHEADS + hd) * SEQLEN + npos) * HDIM;
                    Orow[outc] = f16u(y);
                }
            }
        }
    }
}

// ---------------------------------------------------------------------------
// MFMA flash attention (f16). 128-q blocks (grid 512, 2 blocks/CU), 8 waves
// = 4 q-groups (32 q each: qt=0,1) x 2 key-halves. Permuted-K staging (R14)
// so packed P registers form the K=32 B-frag directly. K/V fragments shared
// across qt; running-pointer staging; imm-offset ds_reads, 3 xor-toggled
// base addrs. Flash-merge of key-half partials per qt at the end.
// LDS: buf{0,1} = {K 8KB | V^T 8KB}; merge area 35840B aliases bufs.
// ---------------------------------------------------------------------------
__global__ __launch_bounds__(512, 4) void attn_mfma_kernel(
    const unsigned short* __restrict__ QKV, const float* __restrict__ ropeC,
    const float* __restrict__ ropeS, unsigned short* __restrict__ Y)
{
    __shared__ __align__(16) unsigned char smem[36864];
    const int tid = threadIdx.x;
    const int w   = tid >> 6;
    const int l   = tid & 63;
    const int g   = l >> 4;
    const int lx  = l & 15;
    const int qg  = w & 3;      // q-group: 32 q per wave
    const int kh  = w >> 2;     // key half
    const int fb  = blockIdx.x;
    const int xcd = fb & 7, jj = fb >> 3;
    const int bh  = xcd * 4 + (jj & 3);       // 4 bh per XCD -> K/V L2-local
    const int b   = bh >> 4;
    const int h   = bh & 15;
    const int q0  = (jj >> 2) * 128;

    const unsigned short* Qb  = QKV + (size_t)bh * SEQLEN * HDIM;
    const unsigned short* Kb  = QKV + 4194304 + (size_t)bh * SEQLEN * HDIM;
    const unsigned short* Vtb = QKV + 8388608 + (size_t)bh * SEQLEN * HDIM;  // (d,n)

    f16x8 qf[2][2];
    #pragma unroll
    for (int qt = 0; qt < 2; ++qt) {
        const unsigned short* src = Qb + (size_t)(q0 + qg * 32 + qt * 16 + lx) * HDIM + g * 8;
        qf[qt][0] = *reinterpret_cast<const f16x8*>(src);
        qf[qt][1] = *reinterpret_cast<const f16x8*>(src + 32);
    }
    f16x8 ones8;
    #pragma unroll
    for (int i = 0; i < 8; ++i) ones8[i] = (_Float16)1.0f;

    const float K2 = 0.18033688011112043f;    // 0.125 * log2(e)
    f32x4 oacc[2][4] = {};
    f32x4 lsum[2] = {};
    float mrow[2] = {-1e30f, -1e30f};

    // staging (running pointers); K rows permuted (R14)
    const int srow = tid >> 3;
    const int c8   = tid & 7;
    const int sch  = c8 ^ (srow & 7);
    const int sdst = tid * 16;
    const int kperm = (srow & 32) + (((srow >> 2) & 3) << 3) + (((srow >> 4) & 1) << 2) + (srow & 3);
    const unsigned short* Kp = Kb + (size_t)kperm * HDIM + sch * 8;
    const unsigned short* Vp = Vtb + (size_t)srow * SEQLEN + sch * 8;

    async_copy16(Kp, smem + sdst);
    async_copy16(Vp, smem + 8192 + sdst);
    Kp += 64 * HDIM; Vp += 64;
    __syncthreads();

    // ds_read byte-offset bases (buf0); toggled by ^16384 per tile
    const int sw = (lx & 7) << 4;
    unsigned kb0 = (kh * 32 + lx) * 128 + ((g * 16) ^ sw);
    unsigned kb1 = (kh * 32 + lx) * 128 + ((64 + g * 16) ^ sw);
    unsigned vb0 = 8192 + lx * 128 + ((kh * 64 + g * 16) ^ sw);
    unsigned nst = 16384 + sdst;               // next staging dest

    for (int kt = 0; kt < SEQLEN / 64; ++kt) {
        if (kt + 1 < SEQLEN / 64) {
            async_copy16(Kp, smem + nst);
            async_copy16(Vp, smem + 8192 + nst);
            Kp += 64 * HDIM; Vp += 64;
        }

        // ---- K fragments (shared across qt)
        f16x8 kf00 = *reinterpret_cast<const f16x8*>(&smem[kb0]);
        f16x8 kf01 = *reinterpret_cast<const f16x8*>(&smem[kb1]);
        f16x8 kf10 = *reinterpret_cast<const f16x8*>(&smem[kb0 + 2048]);
        f16x8 kf11 = *reinterpret_cast<const f16x8*>(&smem[kb1 + 2048]);

        f16x8 pfrag[2];
        #pragma unroll
        for (int qt = 0; qt < 2; ++qt) {
            f32x4 s0 = {}, s1 = {};
            __builtin_amdgcn_s_setprio(1);
            s0 = __builtin_amdgcn_mfma_f32_16x16x32_f16(kf00, qf[qt][0], s0, 0, 0, 0);
            s0 = __builtin_amdgcn_mfma_f32_16x16x32_f16(kf01, qf[qt][1], s0, 0, 0, 0);
            s1 = __builtin_amdgcn_mfma_f32_16x16x32_f16(kf10, qf[qt][0], s1, 0, 0, 0);
            s1 = __builtin_amdgcn_mfma_f32_16x16x32_f16(kf11, qf[qt][1], s1, 0, 0, 0);
            __builtin_amdgcn_s_setprio(0);

            float lmax = fmaxf(fmaxf(fmaxf(s0[0], s0[1]), fmaxf(s0[2], s0[3])),
                               fmaxf(fmaxf(s1[0], s1[1]), fmaxf(s1[2], s1[3])));
            bool ok = (lmax <= mrow[qt] + 64.f);
            if (!__all((int)ok)) {
                float m2 = fmaxf(lmax, __shfl_xor(lmax, 16));
                m2 = fmaxf(m2, __shfl_xor(m2, 32));
                float mnew = fmaxf(mrow[qt], m2);
                float sc = exp2f((mrow[qt] - mnew) * K2);
                mrow[qt] = mnew;
                lsum[qt] *= sc;
                #pragma unroll
                for (int c2 = 0; c2 < 4; ++c2) oacc[qt][c2] *= sc;
            }
            float mk = -mrow[qt] * K2;
            #pragma unroll
            for (int r = 0; r < 4; ++r) {
                s0[r] = exp2f(fmaf(s0[r], K2, mk));
                s1[r] = exp2f(fmaf(s1[r], K2, mk));
            }
            u32x4 pw;
            pw[0] = __builtin_bit_cast(unsigned, __builtin_amdgcn_cvt_pkrtz(s0[0], s0[1]));
            pw[1] = __builtin_bit_cast(unsigned, __builtin_amdgcn_cvt_pkrtz(s0[2], s0[3]));
            pw[2] = __builtin_bit_cast(unsigned, __builtin_amdgcn_cvt_pkrtz(s1[0], s1[1]));
            pw[3] = __builtin_bit_cast(unsigned, __builtin_amdgcn_cvt_pkrtz(s1[2], s1[3]));
            pfrag[qt] = __builtin_bit_cast(f16x8, pw);
        }

        // ---- PV (V fragments shared across qt) + ones row-sums
        __builtin_amdgcn_s_setprio(1);
        lsum[0] = __builtin_amdgcn_mfma_f32_16x16x32_f16(ones8, pfrag[0], lsum[0], 0, 0, 0);
        lsum[1] = __builtin_amdgcn_mfma_f32_16x16x32_f16(ones8, pfrag[1], lsum[1], 0, 0, 0);
        #pragma unroll
        for (int c2 = 0; c2 < 4; ++c2) {
            f16x8 vf = *reinterpret_cast<const f16x8*>(&smem[vb0 + c2 * 2048]);
            oacc[0][c2] = __builtin_amdgcn_mfma_f32_16x16x32_f16(vf, pfrag[0], oacc[0][c2], 0, 0, 0);
            oacc[1][c2] = __builtin_amdgcn_mfma_f32_16x16x32_f16(vf, pfrag[1], oacc[1][c2], 0, 0, 0);
        }
        __builtin_amdgcn_s_setprio(0);

        __syncthreads();
        kb0 ^= 16384; kb1 ^= 16384; vb0 ^= 16384; nst ^= 16384;
    }

    // ---- key-half merge via LDS (flash-merge), then -rope epilogue
    if (kh == 1) {
        #pragma unroll
        for (int qt = 0; qt < 2; ++qt) {
            float* Of = (float*)smem + (qg * 2 + qt) * 1120;
            #pragma unroll
            for (int c2 = 0; c2 < 4; ++c2)
                *reinterpret_cast<f32x4*>(&Of[lx * 68 + c2 * 16 + g * 4]) = oacc[qt][c2];
            if (g == 0) {
                Of[1088 + lx] = mrow[qt];
                Of[1104 + lx] = lsum[qt][0];
            }
        }
    }
    __syncthreads();
    if (kh == 0) {
        #pragma unroll
        for (int qt = 0; qt < 2; ++qt) {
            float* Of = (float*)smem + (qg * 2 + qt) * 1120;
            float m_hi = Of[1088 + lx];
            float l_hi = Of[1104 + lx];
            float M = fmaxf(mrow[qt], m_hi);
            float a  = exp2f((mrow[qt] - M) * K2);
            float bb = exp2f((m_hi - M) * K2);
            float inv = 1.0f / (a * lsum[qt][0] + bb * l_hi);
            const int q = q0 + qg * 32 + qt * 16 + lx;
            unsigned short* drow = Y + ((size_t)b * SEQLEN + q) * DIMSZ + h * HDIM;
            #pragma unroll
            for (int c2 = 0; c2 < 4; ++c2) {
                f32x4 ohi = *reinterpret_cast<const f32x4*>(&Of[lx * 68 + c2 * 16 + g * 4]);
                const float* tab = ((c2 < 2) ? ropeC : ropeS) + (size_t)q * 32;
                unsigned short lo16[2], hi16[2];
                #pragma unroll
                for (int rp = 0; rp < 2; ++rp) {
                    int d = c2 * 16 + g * 4 + 2 * rp;        // even d
                    float v0 = (a * oacc[qt][c2][2 * rp]     + bb * ohi[2 * rp])     * inv;
                    float v1 = (a * oacc[qt][c2][2 * rp + 1] + bb * ohi[2 * rp + 1]) * inv;
                    float Rd = tab[d & 31], Rn = tab[(d & 31) + 1];
                    lo16[rp] = f16u(-(v0 * Rd - v1 * Rn));
                    hi16[rp] = f16u(-(v0 * Rn + v1 * Rd));
                }
                int p = c2 * 8 + g * 2;                       // even column
                *reinterpret_cast<unsigned*>(&drow[p])      = (unsigned)lo16[0] | ((unsigned)lo16[1] << 16);
                *reinterpret_cast<unsigned*>(&drow[p + 32]) = (unsigned)hi16[0] | ((unsigned)hi16[1] << 16);
            }
        }
    }
}

// ---------------------------------------------------------------------------
// Out GEMM: out[4096 x 1024] = Y16 @ Wo16^T + bo (f32 out).
// ---------------------------------------------------------------------------
__global__ __launch_bounds__(512, 4) void out_gemm_kernel(
    const unsigned short* __restrict__ A, const unsigned short* __restrict__ B,
    const float* __restrict__ bias, float* __restrict__ Out)
{
    __shared__ __align__(16) unsigned char smem[65536];
    const int tid = threadIdx.x;
    const int w = tid >> 6, l = tid & 63;
    const int g = l >> 4, lx = l & 15;
    const int wr = w >> 2, wc = w & 3;
    const int row0 = blockIdx.y * 128;
    const int col0 = blockIdx.x * 128;
    const unsigned short* Ab = A + (size_t)row0 * DIMSZ;
    const unsigned short* Bb = B + (size_t)col0 * DIMSZ;

    const int sr = tid >> 3;
    const int sc = tid & 7;
    const int ssw = sc ^ (sr & 7);
    const size_t sAoff0 = (size_t)sr * DIMSZ + ssw * 8;
    const size_t sAoff1 = (size_t)(64 + sr) * DIMSZ + ssw * 8;

    f32x4 acc[4][2] = {};
    async_copy16(Ab + sAoff0, smem + tid * 16);
    async_copy16(Ab + sAoff1, smem + 8192 + tid * 16);
    async_copy16(Bb + sAoff0, smem + 16384 + tid * 16);
    async_copy16(Bb + sAoff1, smem + 16384 + 8192 + tid * 16);
    __syncthreads();

    int buf = 0;
    for (int k0 = 0; k0 < DIMSZ; k0 += 64) {
        if (k0 + 64 < DIMSZ) {
            const int nb = (buf ^ 1) * 32768;
            async_copy16(Ab + sAoff0 + k0 + 64, smem + nb + tid * 16);
            async_copy16(Ab + sAoff1 + k0 + 64, smem + nb + 8192 + tid * 16);
            async_copy16(Bb + sAoff0 + k0 + 64, smem + nb + 16384 + tid * 16);
            async_copy16(Bb + sAoff1 + k0 + 64, smem + nb + 16384 + 8192 + tid * 16);
        }
        const int ab = buf * 32768, bb2 = ab + 16384;
        #pragma unroll
        for (int ks = 0; ks < 2; ++ks) {
            f16x8 af[4], bf[2];
            #pragma unroll
            for (int m = 0; m < 4; ++m) {
                int r = wr * 64 + m * 16 + lx;
                af[m] = *reinterpret_cast<const f16x8*>(
                    &smem[ab + r * 128 + ((ks * 64 + g * 16) ^ ((r & 7) << 4))]);
            }
            #pragma unroll
            for (int n = 0; n < 2; ++n) {
                int r = wc * 32 + n * 16 + lx;
                bf[n] = *reinterpret_cast<const f16x8*>(
                    &smem[bb2 + r * 128 + ((ks * 64 + g * 16) ^ ((r & 7) << 4))]);
            }
            #pragma unroll
            for (int m = 0; m < 4; ++m)
                #pragma unroll
                for (int n = 0; n < 2; ++n)
                    acc[m][n] = __builtin_amdgcn_mfma_f32_16x16x32_f16(af[m], bf[n], acc[m][n], 0, 0, 0);
        }
        __syncthreads();
        buf ^= 1;
    }

    const int cb0 = col0 + wc * 32;
    float bsv[2];
    #pragma unroll
    for (int n = 0; n < 2; ++n) bsv[n] = bias[cb0 + n * 16 + lx];
    #pragma unroll
    for (int m = 0; m < 4; ++m) {
        int rbase = row0 + wr * 64 + m * 16 + g * 4;
        #pragma unroll
        for (int r2 = 0; r2 < 4; ++r2) {
            float* orow = Out + (size_t)(rbase + r2) * DIMSZ + cb0;
            #pragma unroll
            for (int n = 0; n < 2; ++n)
                orow[n * 16 + lx] = acc[m][n][r2] + bsv[n];
        }
    }
}

extern "C" void kernel_launch(void* const* d_in, const int* in_sizes, int n_in,
                              void* d_out, int out_size, void* d_ws, size_t ws_size,
                              hipStream_t stream) {
    const float* x  = (const float*)d_in[0];
    const float* Wq = (const float*)d_in[1];
    const float* bq = (const float*)d_in[2];
    const float* Wk = (const float*)d_in[3];
    const float* bk = (const float*)d_in[4];
    const float* Wv = (const float*)d_in[5];
    const float* bv = (const float*)d_in[6];
    const float* Wo = (const float*)d_in[7];
    const float* bo = (const float*)d_in[8];
    float* out = (float*)d_out;

    char* ws = (char*)d_ws;
    unsigned short* x16    = (unsigned short*)(ws);
    unsigned short* Wqkv16 = (unsigned short*)(ws + 8388608);
    unsigned short* Wo16   = (unsigned short*)(ws + 14680064);
    float* biasqkv         = (float*)(ws + 16777216);
    float* ropeC           = (float*)(ws + 16793600);
    float* ropeS           = (float*)(ws + 17055744);
    unsigned short* QKVw   = (unsigned short*)(ws + 17825792);
    unsigned short* Yw     = (unsigned short*)(ws + 42991616);

    prep_kernel<<<dim3(2048), dim3(256), 0, stream>>>(x, Wq, Wk, Wv, Wo, bq, bk, bv,
                                                x16, Wqkv16, Wo16, biasqkv, ropeC, ropeS);
    qkv_gemm_kernel<<<dim3(24, 32), dim3(512), 0, stream>>>(x16, Wqkv16, biasqkv, ropeC, ropeS, QKVw);
    attn_mfma_kernel<<<dim3(512), dim3(512), 0, stream>>>(QKVw, ropeC, ropeS, Yw);
    out_gemm_kernel<<<dim3(8, 32), dim3(512), 0, stream>>>(Yw, Wo16, bo, out);
}

// Round 16
// 119.839 us; speedup vs baseline: 1.1351x; 1.1351x over previous
//
#include <hip/hip_runtime.h>
#include <hip/hip_bf16.h>
#include <math.h>

#define NHEADS 16
#define HDIM   64
#define BATCH  2
#define SEQLEN 2048
#define DIMSZ  1024

typedef _Float16 f16x8 __attribute__((ext_vector_type(8)));
typedef float    f32x4 __attribute__((ext_vector_type(4)));
typedef unsigned short u16x8 __attribute__((ext_vector_type(8)));
typedef unsigned int   u32x4 __attribute__((ext_vector_type(4)));

__device__ __forceinline__ float rope_theta(int c) {
    int i = c & 31;
    return (float)pow(10000.0, -(double)i / 32.0);
}
__device__ __forceinline__ unsigned short f16u(float f) {
    _Float16 h = (_Float16)f;
    return *reinterpret_cast<unsigned short*>(&h);
}
__device__ __forceinline__ void async_copy16(const void* gsrc, void* lds) {
    __builtin_amdgcn_global_load_lds(
        (const __attribute__((address_space(1))) unsigned int*)gsrc,
        (__attribute__((address_space(3))) unsigned int*)lds, 16, 0, 0);
}

// ---------------------------------------------------------------------------
// prep: f32->f16 conversions (x, Wq|Wk|Wv concat, Wo), bias concat, rope tables
// ---------------------------------------------------------------------------
__global__ __launch_bounds__(256) void prep_kernel(
    const float* __restrict__ x, const float* __restrict__ Wq,
    const float* __restrict__ Wk, const float* __restrict__ Wv,
    const float* __restrict__ Wo, const float* __restrict__ bq,
    const float* __restrict__ bk, const float* __restrict__ bv,
    unsigned short* __restrict__ x16, unsigned short* __restrict__ Wqkv16,
    unsigned short* __restrict__ Wo16, float* __restrict__ biasqkv,
    float* __restrict__ ropeC, float* __restrict__ ropeS)
{
    const int NV = (4194304 + 4 * 1048576) / 8;   // 1,048,576 vec8 chunks
    int gid = blockIdx.x * 256 + threadIdx.x;
    for (int i = gid; i < NV; i += gridDim.x * 256) {
        long e = (long)i * 8;
        const float* src; unsigned short* dst; long off;
        if (e < 4194304)      { src = x;  dst = x16;              off = e; }
        else if (e < 5242880) { src = Wq; dst = Wqkv16;           off = e - 4194304; }
        else if (e < 6291456) { src = Wk; dst = Wqkv16 + 1048576; off = e - 5242880; }
        else if (e < 7340032) { src = Wv; dst = Wqkv16 + 2097152; off = e - 6291456; }
        else                  { src = Wo; dst = Wo16;             off = e - 7340032; }
        float4 v0 = *reinterpret_cast<const float4*>(src + off);
        float4 v1 = *reinterpret_cast<const float4*>(src + off + 4);
        u16x8 o;
        o[0] = f16u(v0.x); o[1] = f16u(v0.y); o[2] = f16u(v0.z); o[3] = f16u(v0.w);
        o[4] = f16u(v1.x); o[5] = f16u(v1.y); o[6] = f16u(v1.z); o[7] = f16u(v1.w);
        *reinterpret_cast<u16x8*>(dst + off) = o;
    }
    if (gid < 65536) {
        int npos = gid >> 5, j = gid & 31;
        float f = (float)npos * rope_theta(j);
        ropeC[gid] = cosf(f);
        ropeS[gid] = sinf(f);
    }
    if (gid < 3072) {
        biasqkv[gid] = gid < 1024 ? bq[gid] : (gid < 2048 ? bk[gid - 1024] : bv[gid - 2048]);
    }
}

// ---------------------------------------------------------------------------
// Fused QKV GEMM + bias + (non-standard) rope. 512 thr / 8 waves (64x32
// sub-tiles), double-buffered swizzled LDS, 1 barrier per K-step.
// ---------------------------------------------------------------------------
__global__ __launch_bounds__(512, 4) void qkv_gemm_kernel(
    const unsigned short* __restrict__ A, const unsigned short* __restrict__ B,
    const float* __restrict__ bias, const float* __restrict__ ropeC,
    const float* __restrict__ ropeS, unsigned short* __restrict__ QKV)
{
    __shared__ __align__(16) unsigned char smem[65536];
    const int tid = threadIdx.x;
    const int w = tid >> 6, l = tid & 63;
    const int g = l >> 4, lx = l & 15;
    const int wr = w >> 2, wc = w & 3;        // 2x4 wave grid: 64x32 subtile
    const int row0 = blockIdx.y * 128;
    const int col0 = blockIdx.x * 128;
    const unsigned short* Ab = A + (size_t)row0 * DIMSZ;
    const unsigned short* Bb = B + (size_t)col0 * DIMSZ;

    const int sr = tid >> 3;                   // 0..63
    const int sc = tid & 7;
    const int ssw = sc ^ (sr & 7);
    const size_t sAoff0 = (size_t)sr * DIMSZ + ssw * 8;
    const size_t sAoff1 = (size_t)(64 + sr) * DIMSZ + ssw * 8;

    f32x4 acc[4][2] = {};
    async_copy16(Ab + sAoff0, smem + tid * 16);
    async_copy16(Ab + sAoff1, smem + 8192 + tid * 16);
    async_copy16(Bb + sAoff0, smem + 16384 + tid * 16);
    async_copy16(Bb + sAoff1, smem + 16384 + 8192 + tid * 16);
    __syncthreads();

    int buf = 0;
    for (int k0 = 0; k0 < DIMSZ; k0 += 64) {
        if (k0 + 64 < DIMSZ) {
            const int nb = (buf ^ 1) * 32768;
            async_copy16(Ab + sAoff0 + k0 + 64, smem + nb + tid * 16);
            async_copy16(Ab + sAoff1 + k0 + 64, smem + nb + 8192 + tid * 16);
            async_copy16(Bb + sAoff0 + k0 + 64, smem + nb + 16384 + tid * 16);
            async_copy16(Bb + sAoff1 + k0 + 64, smem + nb + 16384 + 8192 + tid * 16);
        }
        const int ab = buf * 32768, bb2 = ab + 16384;
        #pragma unroll
        for (int ks = 0; ks < 2; ++ks) {
            f16x8 af[4], bf[2];
            #pragma unroll
            for (int m = 0; m < 4; ++m) {
                int r = wr * 64 + m * 16 + lx;
                af[m] = *reinterpret_cast<const f16x8*>(
                    &smem[ab + r * 128 + ((ks * 64 + g * 16) ^ ((r & 7) << 4))]);
            }
            #pragma unroll
            for (int n = 0; n < 2; ++n) {
                int r = wc * 32 + n * 16 + lx;
                bf[n] = *reinterpret_cast<const f16x8*>(
                    &smem[bb2 + r * 128 + ((ks * 64 + g * 16) ^ ((r & 7) << 4))]);
            }
            #pragma unroll
            for (int m = 0; m < 4; ++m)
                #pragma unroll
                for (int n = 0; n < 2; ++n)
                    acc[m][n] = __builtin_amdgcn_mfma_f32_16x16x32_f16(af[m], bf[n], acc[m][n], 0, 0, 0);
        }
        __syncthreads();
        buf ^= 1;
    }

    const int proj = col0 >> 10;               // block-uniform
    const int cin128 = (col0 & 1023);
    float bsv[2];
    #pragma unroll
    for (int n = 0; n < 2; ++n) bsv[n] = bias[col0 + wc * 32 + n * 16 + lx];

    if (proj == 2) {
        _Float16* T = (_Float16*)smem;   // [128][136]
        #pragma unroll
        for (int m = 0; m < 4; ++m) {
            int rl0 = wr * 64 + m * 16 + g * 4;
            #pragma unroll
            for (int r2 = 0; r2 < 4; ++r2) {
                int rlocal = rl0 + r2;
                int npos = (row0 + rlocal) & (SEQLEN - 1);
                const float* rcp = ropeC + npos * 32;
                const float* rsp = ropeS + npos * 32;
                #pragma unroll
                for (int n = 0; n < 2; ++n) {
                    float v = acc[m][n][r2] + bsv[n];
                    float o = __shfl_xor(v, 1);
                    int dcol = wc * 32 + n * 16 + lx;
                    int c = dcol & 63;
                    const float* tab = (c < 32) ? rcp : rsp;
                    float Rd = tab[c & 31];
                    float Rp = tab[(c & 31) ^ 1];
                    float y; int outc;
                    if (c & 1) { y = o * Rd + v * Rp; outc = (c >> 1) + 32; }
                    else       { y = v * Rd - o * Rp; outc = c >> 1; }
                    T[((dcol >> 6) * 64 + outc) * 136 + rlocal] = (_Float16)y;
                }
            }
        }
        __syncthreads();
        int b = row0 >> 11, npos0 = row0 & (SEQLEN - 1);
        int hd0 = cin128 >> 6;
        int trow = tid >> 2;
        int cbase = (tid & 3) * 32;
        int head = hd0 + (trow >> 6);
        int outd = trow & 63;
        unsigned short* vdst = QKV + 8388608 +
            (((size_t)b * NHEADS + head) * HDIM + outd) * SEQLEN + npos0 + cbase;
        #pragma unroll
        for (int i2 = 0; i2 < 4; ++i2) {
            f16x8 val = *reinterpret_cast<const f16x8*>(&T[trow * 136 + cbase + i2 * 8]);
            *reinterpret_cast<f16x8*>(vdst + i2 * 8) = val;
        }
    } else {
        #pragma unroll
        for (int m = 0; m < 4; ++m) {
            int rbase = row0 + wr * 64 + m * 16 + g * 4;
            #pragma unroll
            for (int r2 = 0; r2 < 4; ++r2) {
                int rglob = rbase + r2;
                int b = rglob >> 11, npos = rglob & (SEQLEN - 1);
                const float* rcp = ropeC + npos * 32;
                const float* rsp = ropeS + npos * 32;
                #pragma unroll
                for (int n = 0; n < 2; ++n) {
                    float v = acc[m][n][r2] + bsv[n];
                    float o = __shfl_xor(v, 1);
                    int hd = (cin128 + wc * 32 + n * 16) >> 6;
                    int c = ((wc * 32 + n * 16) & 63) + lx;
                    const float* tab = (c < 32) ? rcp : rsp;
                    float Rd = tab[c & 31];
                    float Rp = tab[(c & 31) ^ 1];
                    float y; int outc;
                    if (c & 1) { y = o * Rd + v * Rp; outc = (c >> 1) + 32; }
                    else       { y = v * Rd - o * Rp; outc = c >> 1; }
                    unsigned short* Orow = QKV +
                        ((((size_t)proj * BATCH + b) * NHEADS + hd) * SEQLEN + npos) * HDIM;
                    Orow[outc] = f16u(y);
                }
            }
        }
    }
}

// ---------------------------------------------------------------------------
// MFMA flash attention (f16). 128-q blocks, 8 waves = 4 q-groups x 2
// key-halves; permuted-K staging so packed P registers form the K=32 B-frag
// directly; K/V fragments shared across qt; native v_exp_f32 via
// __builtin_amdgcn_exp2f (exp2f lowers to guarded __ocml path otherwise).
// ---------------------------------------------------------------------------
__global__ __launch_bounds__(512, 4) void attn_mfma_kernel(
    const unsigned short* __restrict__ QKV, const float* __restrict__ ropeC,
    const float* __restrict__ ropeS, unsigned short* __restrict__ Y)
{
    __shared__ __align__(16) unsigned char smem[36864];
    const int tid = threadIdx.x;
    const int w   = tid >> 6;
    const int l   = tid & 63;
    const int g   = l >> 4;
    const int lx  = l & 15;
    const int qg  = w & 3;      // q-group: 32 q per wave
    const int kh  = w >> 2;     // key half
    const int fb  = blockIdx.x;
    const int xcd = fb & 7, jj = fb >> 3;
    const int bh  = xcd * 4 + (jj & 3);       // 4 bh per XCD -> K/V L2-local
    const int b   = bh >> 4;
    const int h   = bh & 15;
    const int q0  = (jj >> 2) * 128;

    const unsigned short* Qb  = QKV + (size_t)bh * SEQLEN * HDIM;
    const unsigned short* Kb  = QKV + 4194304 + (size_t)bh * SEQLEN * HDIM;
    const unsigned short* Vtb = QKV + 8388608 + (size_t)bh * SEQLEN * HDIM;  // (d,n)

    f16x8 qf[2][2];
    #pragma unroll
    for (int qt = 0; qt < 2; ++qt) {
        const unsigned short* src = Qb + (size_t)(q0 + qg * 32 + qt * 16 + lx) * HDIM + g * 8;
        qf[qt][0] = *reinterpret_cast<const f16x8*>(src);
        qf[qt][1] = *reinterpret_cast<const f16x8*>(src + 32);
    }
    f16x8 ones8;
    #pragma unroll
    for (int i = 0; i < 8; ++i) ones8[i] = (_Float16)1.0f;

    const float K2 = 0.18033688011112043f;    // 0.125 * log2(e)
    f32x4 oacc[2][4] = {};
    f32x4 lsum[2] = {};
    float mrow[2] = {-1e30f, -1e30f};

    // staging (running pointers); K rows permuted (R14)
    const int srow = tid >> 3;
    const int c8   = tid & 7;
    const int sch  = c8 ^ (srow & 7);
    const int sdst = tid * 16;
    const int kperm = (srow & 32) + (((srow >> 2) & 3) << 3) + (((srow >> 4) & 1) << 2) + (srow & 3);
    const unsigned short* Kp = Kb + (size_t)kperm * HDIM + sch * 8;
    const unsigned short* Vp = Vtb + (size_t)srow * SEQLEN + sch * 8;

    async_copy16(Kp, smem + sdst);
    async_copy16(Vp, smem + 8192 + sdst);
    Kp += 64 * HDIM; Vp += 64;
    __syncthreads();

    // ds_read byte-offset bases (buf0); toggled by ^16384 per tile
    const int sw = (lx & 7) << 4;
    unsigned kb0 = (kh * 32 + lx) * 128 + ((g * 16) ^ sw);
    unsigned kb1 = (kh * 32 + lx) * 128 + ((64 + g * 16) ^ sw);
    unsigned vb0 = 8192 + lx * 128 + ((kh * 64 + g * 16) ^ sw);
    unsigned nst = 16384 + sdst;               // next staging dest

    for (int kt = 0; kt < SEQLEN / 64; ++kt) {
        if (kt + 1 < SEQLEN / 64) {
            async_copy16(Kp, smem + nst);
            async_copy16(Vp, smem + 8192 + nst);
            Kp += 64 * HDIM; Vp += 64;
        }

        // ---- K fragments (shared across qt)
        f16x8 kf00 = *reinterpret_cast<const f16x8*>(&smem[kb0]);
        f16x8 kf01 = *reinterpret_cast<const f16x8*>(&smem[kb1]);
        f16x8 kf10 = *reinterpret_cast<const f16x8*>(&smem[kb0 + 2048]);
        f16x8 kf11 = *reinterpret_cast<const f16x8*>(&smem[kb1 + 2048]);

        f16x8 pfrag[2];
        #pragma unroll
        for (int qt = 0; qt < 2; ++qt) {
            f32x4 s0 = {}, s1 = {};
            __builtin_amdgcn_s_setprio(1);
            s0 = __builtin_amdgcn_mfma_f32_16x16x32_f16(kf00, qf[qt][0], s0, 0, 0, 0);
            s0 = __builtin_amdgcn_mfma_f32_16x16x32_f16(kf01, qf[qt][1], s0, 0, 0, 0);
            s1 = __builtin_amdgcn_mfma_f32_16x16x32_f16(kf10, qf[qt][0], s1, 0, 0, 0);
            s1 = __builtin_amdgcn_mfma_f32_16x16x32_f16(kf11, qf[qt][1], s1, 0, 0, 0);
            __builtin_amdgcn_s_setprio(0);

            float lmax = fmaxf(fmaxf(fmaxf(s0[0], s0[1]), fmaxf(s0[2], s0[3])),
                               fmaxf(fmaxf(s1[0], s1[1]), fmaxf(s1[2], s1[3])));
            bool ok = (lmax <= mrow[qt] + 64.f);
            if (!__all((int)ok)) {
                float m2 = fmaxf(lmax, __shfl_xor(lmax, 16));
                m2 = fmaxf(m2, __shfl_xor(m2, 32));
                float mnew = fmaxf(mrow[qt], m2);
                float sc = __builtin_amdgcn_exp2f((mrow[qt] - mnew) * K2);
                mrow[qt] = mnew;
                lsum[qt] *= sc;
                #pragma unroll
                for (int c2 = 0; c2 < 4; ++c2) oacc[qt][c2] *= sc;
            }
            float mk = -mrow[qt] * K2;
            #pragma unroll
            for (int r = 0; r < 4; ++r) {
                s0[r] = __builtin_amdgcn_exp2f(fmaf(s0[r], K2, mk));
                s1[r] = __builtin_amdgcn_exp2f(fmaf(s1[r], K2, mk));
            }
            u32x4 pw;
            pw[0] = __builtin_bit_cast(unsigned, __builtin_amdgcn_cvt_pkrtz(s0[0], s0[1]));
            pw[1] = __builtin_bit_cast(unsigned, __builtin_amdgcn_cvt_pkrtz(s0[2], s0[3]));
            pw[2] = __builtin_bit_cast(unsigned, __builtin_amdgcn_cvt_pkrtz(s1[0], s1[1]));
            pw[3] = __builtin_bit_cast(unsigned, __builtin_amdgcn_cvt_pkrtz(s1[2], s1[3]));
            pfrag[qt] = __builtin_bit_cast(f16x8, pw);
        }

        // ---- PV (V fragments shared across qt) + ones row-sums
        __builtin_amdgcn_s_setprio(1);
        lsum[0] = __builtin_amdgcn_mfma_f32_16x16x32_f16(ones8, pfrag[0], lsum[0], 0, 0, 0);
        lsum[1] = __builtin_amdgcn_mfma_f32_16x16x32_f16(ones8, pfrag[1], lsum[1], 0, 0, 0);
        #pragma unroll
        for (int c2 = 0; c2 < 4; ++c2) {
            f16x8 vf = *reinterpret_cast<const f16x8*>(&smem[vb0 + c2 * 2048]);
            oacc[0][c2] = __builtin_amdgcn_mfma_f32_16x16x32_f16(vf, pfrag[0], oacc[0][c2], 0, 0, 0);
            oacc[1][c2] = __builtin_amdgcn_mfma_f32_16x16x32_f16(vf, pfrag[1], oacc[1][c2], 0, 0, 0);
        }
        __builtin_amdgcn_s_setprio(0);

        __syncthreads();
        kb0 ^= 16384; kb1 ^= 16384; vb0 ^= 16384; nst ^= 16384;
    }

    // ---- key-half merge via LDS (flash-merge), then -rope epilogue
    if (kh == 1) {
        #pragma unroll
        for (int qt = 0; qt < 2; ++qt) {
            float* Of = (float*)smem + (qg * 2 + qt) * 1120;
            #pragma unroll
            for (int c2 = 0; c2 < 4; ++c2)
                *reinterpret_cast<f32x4*>(&Of[lx * 68 + c2 * 16 + g * 4]) = oacc[qt][c2];
            if (g == 0) {
                Of[1088 + lx] = mrow[qt];
                Of[1104 + lx] = lsum[qt][0];
            }
        }
    }
    __syncthreads();
    if (kh == 0) {
        #pragma unroll
        for (int qt = 0; qt < 2; ++qt) {
            float* Of = (float*)smem + (qg * 2 + qt) * 1120;
            float m_hi = Of[1088 + lx];
            float l_hi = Of[1104 + lx];
            float M = fmaxf(mrow[qt], m_hi);
            float a  = __builtin_amdgcn_exp2f((mrow[qt] - M) * K2);
            float bb = __builtin_amdgcn_exp2f((m_hi - M) * K2);
            float inv = 1.0f / (a * lsum[qt][0] + bb * l_hi);
            const int q = q0 + qg * 32 + qt * 16 + lx;
            unsigned short* drow = Y + ((size_t)b * SEQLEN + q) * DIMSZ + h * HDIM;
            #pragma unroll
            for (int c2 = 0; c2 < 4; ++c2) {
                f32x4 ohi = *reinterpret_cast<const f32x4*>(&Of[lx * 68 + c2 * 16 + g * 4]);
                const float* tab = ((c2 < 2) ? ropeC : ropeS) + (size_t)q * 32;
                unsigned short lo16[2], hi16[2];
                #pragma unroll
                for (int rp = 0; rp < 2; ++rp) {
                    int d = c2 * 16 + g * 4 + 2 * rp;        // even d
                    float v0 = (a * oacc[qt][c2][2 * rp]     + bb * ohi[2 * rp])     * inv;
                    float v1 = (a * oacc[qt][c2][2 * rp + 1] + bb * ohi[2 * rp + 1]) * inv;
                    float Rd = tab[d & 31], Rn = tab[(d & 31) + 1];
                    lo16[rp] = f16u(-(v0 * Rd - v1 * Rn));
                    hi16[rp] = f16u(-(v0 * Rn + v1 * Rd));
                }
                int p = c2 * 8 + g * 2;                       // even column
                *reinterpret_cast<unsigned*>(&drow[p])      = (unsigned)lo16[0] | ((unsigned)lo16[1] << 16);
                *reinterpret_cast<unsigned*>(&drow[p + 32]) = (unsigned)hi16[0] | ((unsigned)hi16[1] << 16);
            }
        }
    }
}

// ---------------------------------------------------------------------------
// Out GEMM: out[4096 x 1024] = Y16 @ Wo16^T + bo (f32 out).
// ---------------------------------------------------------------------------
__global__ __launch_bounds__(512, 4) void out_gemm_kernel(
    const unsigned short* __restrict__ A, const unsigned short* __restrict__ B,
    const float* __restrict__ bias, float* __restrict__ Out)
{
    __shared__ __align__(16) unsigned char smem[65536];
    const int tid = threadIdx.x;
    const int w = tid >> 6, l = tid & 63;
    const int g = l >> 4, lx = l & 15;
    const int wr = w >> 2, wc = w & 3;
    const int row0 = blockIdx.y * 128;
    const int col0 = blockIdx.x * 128;
    const unsigned short* Ab = A + (size_t)row0 * DIMSZ;
    const unsigned short* Bb = B + (size_t)col0 * DIMSZ;

    const int sr = tid >> 3;
    const int sc = tid & 7;
    const int ssw = sc ^ (sr & 7);
    const size_t sAoff0 = (size_t)sr * DIMSZ + ssw * 8;
    const size_t sAoff1 = (size_t)(64 + sr) * DIMSZ + ssw * 8;

    f32x4 acc[4][2] = {};
    async_copy16(Ab + sAoff0, smem + tid * 16);
    async_copy16(Ab + sAoff1, smem + 8192 + tid * 16);
    async_copy16(Bb + sAoff0, smem + 16384 + tid * 16);
    async_copy16(Bb + sAoff1, smem + 16384 + 8192 + tid * 16);
    __syncthreads();

    int buf = 0;
    for (int k0 = 0; k0 < DIMSZ; k0 += 64) {
        if (k0 + 64 < DIMSZ) {
            const int nb = (buf ^ 1) * 32768;
            async_copy16(Ab + sAoff0 + k0 + 64, smem + nb + tid * 16);
            async_copy16(Ab + sAoff1 + k0 + 64, smem + nb + 8192 + tid * 16);
            async_copy16(Bb + sAoff0 + k0 + 64, smem + nb + 16384 + tid * 16);
            async_copy16(Bb + sAoff1 + k0 + 64, smem + nb + 16384 + 8192 + tid * 16);
        }
        const int ab = buf * 32768, bb2 = ab + 16384;
        #pragma unroll
        for (int ks = 0; ks < 2; ++ks) {
            f16x8 af[4], bf[2];
            #pragma unroll
            for (int m = 0; m < 4; ++m) {
                int r = wr * 64 + m * 16 + lx;
                af[m] = *reinterpret_cast<const f16x8*>(
                    &smem[ab + r * 128 + ((ks * 64 + g * 16) ^ ((r & 7) << 4))]);
            }
            #pragma unroll
            for (int n = 0; n < 2; ++n) {
                int r = wc * 32 + n * 16 + lx;
                bf[n] = *reinterpret_cast<const f16x8*>(
                    &smem[bb2 + r * 128 + ((ks * 64 + g * 16) ^ ((r & 7) << 4))]);
            }
            #pragma unroll
            for (int m = 0; m < 4; ++m)
                #pragma unroll
                for (int n = 0; n < 2; ++n)
                    acc[m][n] = __builtin_amdgcn_mfma_f32_16x16x32_f16(af[m], bf[n], acc[m][n], 0, 0, 0);
        }
        __syncthreads();
        buf ^= 1;
    }

    const int cb0 = col0 + wc * 32;
    float bsv[2];
    #pragma unroll
    for (int n = 0; n < 2; ++n) bsv[n] = bias[cb0 + n * 16 + lx];
    #pragma unroll
    for (int m = 0; m < 4; ++m) {
        int rbase = row0 + wr * 64 + m * 16 + g * 4;
        #pragma unroll
        for (int r2 = 0; r2 < 4; ++r2) {
            float* orow = Out + (size_t)(rbase + r2) * DIMSZ + cb0;
            #pragma unroll
            for (int n = 0; n < 2; ++n)
                orow[n * 16 + lx] = acc[m][n][r2] + bsv[n];
        }
    }
}

extern "C" void kernel_launch(void* const* d_in, const int* in_sizes, int n_in,
                              void* d_out, int out_size, void* d_ws, size_t ws_size,
                              hipStream_t stream) {
    const float* x  = (const float*)d_in[0];
    const float* Wq = (const float*)d_in[1];
    const float* bq = (const float*)d_in[2];
    const float* Wk = (const float*)d_in[3];
    const float* bk = (const float*)d_in[4];
    const float* Wv = (const float*)d_in[5];
    const float* bv = (const float*)d_in[6];
    const float* Wo = (const float*)d_in[7];
    const float* bo = (const float*)d_in[8];
    float* out = (float*)d_out;

    char* ws = (char*)d_ws;
    unsigned short* x16    = (unsigned short*)(ws);
    unsigned short* Wqkv16 = (unsigned short*)(ws + 8388608);
    unsigned short* Wo16   = (unsigned short*)(ws + 14680064);
    float* biasqkv         = (float*)(ws + 16777216);
    float* ropeC           = (float*)(ws + 16793600);
    float* ropeS           = (float*)(ws + 17055744);
    unsigned short* QKVw   = (unsigned short*)(ws + 17825792);
    unsigned short* Yw     = (unsigned short*)(ws + 42991616);

    prep_kernel<<<dim3(2048), dim3(256), 0, stream>>>(x, Wq, Wk, Wv, Wo, bq, bk, bv,
                                                x16, Wqkv16, Wo16, biasqkv, ropeC, ropeS);
    qkv_gemm_kernel<<<dim3(24, 32), dim3(512), 0, stream>>>(x16, Wqkv16, biasqkv, ropeC, ropeS, QKVw);
    attn_mfma_kernel<<<dim3(512), dim3(512), 0, stream>>>(QKVw, ropeC, ropeS, Yw);
    out_gemm_kernel<<<dim3(8, 32), dim3(512), 0, stream>>>(Yw, Wo16, bo, out);
}

// Round 18
// 117.387 us; speedup vs baseline: 1.1589x; 1.0209x over previous
//
#include <hip/hip_runtime.h>
#include <hip/hip_bf16.h>
#include <math.h>

#define NHEADS 16
#define HDIM   64
#define BATCH  2
#define SEQLEN 2048
#define DIMSZ  1024

typedef _Float16 f16x8 __attribute__((ext_vector_type(8)));
typedef float    f32x4 __attribute__((ext_vector_type(4)));
typedef unsigned short u16x8 __attribute__((ext_vector_type(8)));
typedef unsigned int   u32x4 __attribute__((ext_vector_type(4)));

__device__ __forceinline__ float rope_theta(int c) {
    int i = c & 31;
    return (float)pow(10000.0, -(double)i / 32.0);
}
__device__ __forceinline__ unsigned short f16u(float f) {
    _Float16 h = (_Float16)f;
    return *reinterpret_cast<unsigned short*>(&h);
}
__device__ __forceinline__ void async_copy16(const void* gsrc, void* lds) {
    __builtin_amdgcn_global_load_lds(
        (const __attribute__((address_space(1))) unsigned int*)gsrc,
        (__attribute__((address_space(3))) unsigned int*)lds, 16, 0, 0);
}

// ---------------------------------------------------------------------------
// prep: f32->f16 conversions (x, Wq|Wk|Wv concat, Wo), bias concat, rope tables
// ---------------------------------------------------------------------------
__global__ __launch_bounds__(256) void prep_kernel(
    const float* __restrict__ x, const float* __restrict__ Wq,
    const float* __restrict__ Wk, const float* __restrict__ Wv,
    const float* __restrict__ Wo, const float* __restrict__ bq,
    const float* __restrict__ bk, const float* __restrict__ bv,
    unsigned short* __restrict__ x16, unsigned short* __restrict__ Wqkv16,
    unsigned short* __restrict__ Wo16, float* __restrict__ biasqkv,
    float* __restrict__ ropeC, float* __restrict__ ropeS)
{
    const int NV = (4194304 + 4 * 1048576) / 8;   // 1,048,576 vec8 chunks
    int gid = blockIdx.x * 256 + threadIdx.x;
    for (int i = gid; i < NV; i += gridDim.x * 256) {
        long e = (long)i * 8;
        const float* src; unsigned short* dst; long off;
        if (e < 4194304)      { src = x;  dst = x16;              off = e; }
        else if (e < 5242880) { src = Wq; dst = Wqkv16;           off = e - 4194304; }
        else if (e < 6291456) { src = Wk; dst = Wqkv16 + 1048576; off = e - 5242880; }
        else if (e < 7340032) { src = Wv; dst = Wqkv16 + 2097152; off = e - 6291456; }
        else                  { src = Wo; dst = Wo16;             off = e - 7340032; }
        float4 v0 = *reinterpret_cast<const float4*>(src + off);
        float4 v1 = *reinterpret_cast<const float4*>(src + off + 4);
        u16x8 o;
        o[0] = f16u(v0.x); o[1] = f16u(v0.y); o[2] = f16u(v0.z); o[3] = f16u(v0.w);
        o[4] = f16u(v1.x); o[5] = f16u(v1.y); o[6] = f16u(v1.z); o[7] = f16u(v1.w);
        *reinterpret_cast<u16x8*>(dst + off) = o;
    }
    if (gid < 65536) {
        int npos = gid >> 5, j = gid & 31;
        float f = (float)npos * rope_theta(j);
        ropeC[gid] = cosf(f);
        ropeS[gid] = sinf(f);
    }
    if (gid < 3072) {
        biasqkv[gid] = gid < 1024 ? bq[gid] : (gid < 2048 ? bk[gid - 1024] : bv[gid - 2048]);
    }
}

// ---------------------------------------------------------------------------
// Fused QKV GEMM + bias + (non-standard) rope. 512 thr / 8 waves (64x32
// sub-tiles), double-buffered swizzled LDS, 1 barrier per K-step.
// ---------------------------------------------------------------------------
__global__ __launch_bounds__(512, 4) void qkv_gemm_kernel(
    const unsigned short* __restrict__ A, const unsigned short* __restrict__ B,
    const float* __restrict__ bias, const float* __restrict__ ropeC,
    const float* __restrict__ ropeS, unsigned short* __restrict__ QKV)
{
    __shared__ __align__(16) unsigned char smem[65536];
    const int tid = threadIdx.x;
    const int w = tid >> 6, l = tid & 63;
    const int g = l >> 4, lx = l & 15;
    const int wr = w >> 2, wc = w & 3;        // 2x4 wave grid: 64x32 subtile
    const int row0 = blockIdx.y * 128;
    const int col0 = blockIdx.x * 128;
    const unsigned short* Ab = A + (size_t)row0 * DIMSZ;
    const unsigned short* Bb = B + (size_t)col0 * DIMSZ;

    const int sr = tid >> 3;                   // 0..63
    const int sc = tid & 7;
    const int ssw = sc ^ (sr & 7);
    const size_t sAoff0 = (size_t)sr * DIMSZ + ssw * 8;
    const size_t sAoff1 = (size_t)(64 + sr) * DIMSZ + ssw * 8;

    f32x4 acc[4][2] = {};
    async_copy16(Ab + sAoff0, smem + tid * 16);
    async_copy16(Ab + sAoff1, smem + 8192 + tid * 16);
    async_copy16(Bb + sAoff0, smem + 16384 + tid * 16);
    async_copy16(Bb + sAoff1, smem + 16384 + 8192 + tid * 16);
    __syncthreads();

    int buf = 0;
    for (int k0 = 0; k0 < DIMSZ; k0 += 64) {
        if (k0 + 64 < DIMSZ) {
            const int nb = (buf ^ 1) * 32768;
            async_copy16(Ab + sAoff0 + k0 + 64, smem + nb + tid * 16);
            async_copy16(Ab + sAoff1 + k0 + 64, smem + nb + 8192 + tid * 16);
            async_copy16(Bb + sAoff0 + k0 + 64, smem + nb + 16384 + tid * 16);
            async_copy16(Bb + sAoff1 + k0 + 64, smem + nb + 16384 + 8192 + tid * 16);
        }
        const int ab = buf * 32768, bb2 = ab + 16384;
        #pragma unroll
        for (int ks = 0; ks < 2; ++ks) {
            f16x8 af[4], bf[2];
            #pragma unroll
            for (int m = 0; m < 4; ++m) {
                int r = wr * 64 + m * 16 + lx;
                af[m] = *reinterpret_cast<const f16x8*>(
                    &smem[ab + r * 128 + ((ks * 64 + g * 16) ^ ((r & 7) << 4))]);
            }
            #pragma unroll
            for (int n = 0; n < 2; ++n) {
                int r = wc * 32 + n * 16 + lx;
                bf[n] = *reinterpret_cast<const f16x8*>(
                    &smem[bb2 + r * 128 + ((ks * 64 + g * 16) ^ ((r & 7) << 4))]);
            }
            #pragma unroll
            for (int m = 0; m < 4; ++m)
                #pragma unroll
                for (int n = 0; n < 2; ++n)
                    acc[m][n] = __builtin_amdgcn_mfma_f32_16x16x32_f16(af[m], bf[n], acc[m][n], 0, 0, 0);
        }
        __syncthreads();
        buf ^= 1;
    }

    const int proj = col0 >> 10;               // block-uniform
    const int cin128 = (col0 & 1023);
    float bsv[2];
    #pragma unroll
    for (int n = 0; n < 2; ++n) bsv[n] = bias[col0 + wc * 32 + n * 16 + lx];

    if (proj == 2) {
        _Float16* T = (_Float16*)smem;   // [128][136]
        #pragma unroll
        for (int m = 0; m < 4; ++m) {
            int rl0 = wr * 64 + m * 16 + g * 4;
            #pragma unroll
            for (int r2 = 0; r2 < 4; ++r2) {
                int rlocal = rl0 + r2;
                int npos = (row0 + rlocal) & (SEQLEN - 1);
                const float* rcp = ropeC + npos * 32;
                const float* rsp = ropeS + npos * 32;
                #pragma unroll
                for (int n = 0; n < 2; ++n) {
                    float v = acc[m][n][r2] + bsv[n];
                    float o = __shfl_xor(v, 1);
                    int dcol = wc * 32 + n * 16 + lx;
                    int c = dcol & 63;
                    const float* tab = (c < 32) ? rcp : rsp;
                    float Rd = tab[c & 31];
                    float Rp = tab[(c & 31) ^ 1];
                    float y; int outc;
                    if (c & 1) { y = o * Rd + v * Rp; outc = (c >> 1) + 32; }
                    else       { y = v * Rd - o * Rp; outc = c >> 1; }
                    T[((dcol >> 6) * 64 + outc) * 136 + rlocal] = (_Float16)y;
                }
            }
        }
        __syncthreads();
        int b = row0 >> 11, npos0 = row0 & (SEQLEN - 1);
        int hd0 = cin128 >> 6;
        int trow = tid >> 2;
        int cbase = (tid & 3) * 32;
        int head = hd0 + (trow >> 6);
        int outd = trow & 63;
        unsigned short* vdst = QKV + 8388608 +
            (((size_t)b * NHEADS + head) * HDIM + outd) * SEQLEN + npos0 + cbase;
        #pragma unroll
        for (int i2 = 0; i2 < 4; ++i2) {
            f16x8 val = *reinterpret_cast<const f16x8*>(&T[trow * 136 + cbase + i2 * 8]);
            *reinterpret_cast<f16x8*>(vdst + i2 * 8) = val;
        }
    } else {
        #pragma unroll
        for (int m = 0; m < 4; ++m) {
            int rbase = row0 + wr * 64 + m * 16 + g * 4;
            #pragma unroll
            for (int r2 = 0; r2 < 4; ++r2) {
                int rglob = rbase + r2;
                int b = rglob >> 11, npos = rglob & (SEQLEN - 1);
                const float* rcp = ropeC + npos * 32;
                const float* rsp = ropeS + npos * 32;
                #pragma unroll
                for (int n = 0; n < 2; ++n) {
                    float v = acc[m][n][r2] + bsv[n];
                    float o = __shfl_xor(v, 1);
                    int hd = (cin128 + wc * 32 + n * 16) >> 6;
                    int c = ((wc * 32 + n * 16) & 63) + lx;
                    const float* tab = (c < 32) ? rcp : rsp;
                    float Rd = tab[c & 31];
                    float Rp = tab[(c & 31) ^ 1];
                    float y; int outc;
                    if (c & 1) { y = o * Rd + v * Rp; outc = (c >> 1) + 32; }
                    else       { y = v * Rd - o * Rp; outc = c >> 1; }
                    unsigned short* Orow = QKV +
                        ((((size_t)proj * BATCH + b) * NHEADS + hd) * SEQLEN + npos) * HDIM;
                    Orow[outc] = f16u(y);
                }
            }
        }
    }
}

// ---------------------------------------------------------------------------
// MFMA flash attention (f16). 128-q blocks x 128-KEY TILES (16 barriers).
// 8 waves = 4 q-groups (32 q: qt=0,1) x 2 key-halves (64 keys each).
// Permuted-K staging per 32-key group so packed P = K=32 B-frag (no shfl).
// V^T rows 256B: LINEAR LDS dest (t*16), inverse-XOR source chunk
// (j ^ (row&15)), XOR on read (rule #21). No setprio (lockstep loop).
// LDS: buf{0,1} = {K 16KB | V^T 16KB} = 64KB; merge area aliases at end.
// ---------------------------------------------------------------------------
__global__ __launch_bounds__(512, 4) void attn_mfma_kernel(
    const unsigned short* __restrict__ QKV, const float* __restrict__ ropeC,
    const float* __restrict__ ropeS, unsigned short* __restrict__ Y)
{
    __shared__ __align__(16) unsigned char smem[65536];
    const int tid = threadIdx.x;
    const int w   = tid >> 6;
    const int l   = tid & 63;
    const int g   = l >> 4;
    const int lx  = l & 15;
    const int qg  = w & 3;      // q-group: 32 q per wave
    const int kh  = w >> 2;     // key half: 64 keys of each 128-key tile
    const int fb  = blockIdx.x;
    const int xcd = fb & 7, jj = fb >> 3;
    const int bh  = xcd * 4 + (jj & 3);       // 4 bh per XCD -> K/V L2-local
    const int b   = bh >> 4;
    const int h   = bh & 15;
    const int q0  = (jj >> 2) * 128;

    const unsigned short* Qb  = QKV + (size_t)bh * SEQLEN * HDIM;
    const unsigned short* Kb  = QKV + 4194304 + (size_t)bh * SEQLEN * HDIM;
    const unsigned short* Vtb = QKV + 8388608 + (size_t)bh * SEQLEN * HDIM;  // (d,n)

    f16x8 qf[2][2];
    #pragma unroll
    for (int qt = 0; qt < 2; ++qt) {
        const unsigned short* src = Qb + (size_t)(q0 + qg * 32 + qt * 16 + lx) * HDIM + g * 8;
        qf[qt][0] = *reinterpret_cast<const f16x8*>(src);
        qf[qt][1] = *reinterpret_cast<const f16x8*>(src + 32);
    }
    f16x8 ones8;
    #pragma unroll
    for (int i = 0; i < 8; ++i) ones8[i] = (_Float16)1.0f;

    const float K2 = 0.18033688011112043f;    // 0.125 * log2(e)
    f32x4 oacc[2][4] = {};
    f32x4 lsum[2] = {};
    float mrow[2] = {-1e30f, -1e30f};

    // ---- K staging: rows permuted per 32-group, linear dest tid*16
    const int srow = tid >> 3;                 // 0..63
    const int c8   = tid & 7;
    const int sch  = c8 ^ (srow & 7);
    const int kperm = (srow & 32) + (((srow >> 2) & 3) << 3) + (((srow >> 4) & 1) << 2) + (srow & 3);
    const unsigned short* Kp = Kb + (size_t)kperm * HDIM + sch * 8;     // +64*HDIM rows 64..127
    // ---- V staging: LINEAR dest; thread t -> row t>>4 (and +32), chunk t&15,
    //      source chunk (t&15) ^ ((t>>4)&15)  [same expr for both instrs]
    const int vrow = tid >> 4;                 // 0..31
    const int vsw  = ((tid & 15) ^ (vrow & 15)) * 8;
    const unsigned short* Vp0 = Vtb + (size_t)vrow * SEQLEN + vsw;
    const unsigned short* Vp1 = Vtb + (size_t)(32 + vrow) * SEQLEN + vsw;

    async_copy16(Kp, smem + tid * 16);
    async_copy16(Kp + 64 * HDIM, smem + 8192 + tid * 16);
    async_copy16(Vp0, smem + 16384 + tid * 16);
    async_copy16(Vp1, smem + 16384 + 8192 + tid * 16);
    Kp += 128 * HDIM; Vp0 += 128; Vp1 += 128;
    __syncthreads();

    // ds_read bases (buf0); toggled ^32768 per tile
    const int sw = (lx & 7) << 4;
    unsigned kb0 = (kh * 64 + lx) * 128 + ((g * 16) ^ sw);
    unsigned kb1 = (kh * 64 + lx) * 128 + ((64 + g * 16) ^ sw);
    unsigned vbr = 16384 + lx * 256;
    unsigned vb0 = vbr + ((kh * 128 + g * 16) ^ (lx << 4));
    unsigned vb1 = vbr + ((kh * 128 + 64 + g * 16) ^ (lx << 4));
    unsigned nstK = 32768 + tid * 16;
    unsigned nstV = 32768 + 16384 + tid * 16;

    for (int kt = 0; kt < 16; ++kt) {
        if (kt < 15) {
            async_copy16(Kp, smem + nstK);
            async_copy16(Kp + 64 * HDIM, smem + nstK + 8192);
            async_copy16(Vp0, smem + nstV);
            async_copy16(Vp1, smem + nstV + 8192);
            Kp += 128 * HDIM; Vp0 += 128; Vp1 += 128;
        }

        // ---- QK^T: s[qt][c], keys perm'd so s[qt][2kg..2kg+1] pack to B-frag
        f32x4 s[2][4] = {};
        #pragma unroll
        for (int c = 0; c < 4; ++c) {
            f16x8 kf0 = *reinterpret_cast<const f16x8*>(&smem[kb0 + c * 2048]);
            f16x8 kf1 = *reinterpret_cast<const f16x8*>(&smem[kb1 + c * 2048]);
            s[0][c] = __builtin_amdgcn_mfma_f32_16x16x32_f16(kf0, qf[0][0], s[0][c], 0, 0, 0);
            s[0][c] = __builtin_amdgcn_mfma_f32_16x16x32_f16(kf1, qf[0][1], s[0][c], 0, 0, 0);
            s[1][c] = __builtin_amdgcn_mfma_f32_16x16x32_f16(kf0, qf[1][0], s[1][c], 0, 0, 0);
            s[1][c] = __builtin_amdgcn_mfma_f32_16x16x32_f16(kf1, qf[1][1], s[1][c], 0, 0, 0);
        }

        // ---- softmax (deferred max) + pack P per qt
        f16x8 pfrag[2][2];
        #pragma unroll
        for (int qt = 0; qt < 2; ++qt) {
            float lmax = s[qt][0][0];
            #pragma unroll
            for (int c = 0; c < 4; ++c)
                #pragma unroll
                for (int r = 0; r < 4; ++r) lmax = fmaxf(lmax, s[qt][c][r]);
            bool ok = (lmax <= mrow[qt] + 64.f);
            if (!__all((int)ok)) {
                float m2 = fmaxf(lmax, __shfl_xor(lmax, 16));
                m2 = fmaxf(m2, __shfl_xor(m2, 32));
                float mnew = fmaxf(mrow[qt], m2);
                float sc = __builtin_amdgcn_exp2f((mrow[qt] - mnew) * K2);
                mrow[qt] = mnew;
                lsum[qt] *= sc;
                #pragma unroll
                for (int c2 = 0; c2 < 4; ++c2) oacc[qt][c2] *= sc;
            }
            float mk = -mrow[qt] * K2;
            #pragma unroll
            for (int c = 0; c < 4; ++c)
                #pragma unroll
                for (int r = 0; r < 4; ++r)
                    s[qt][c][r] = __builtin_amdgcn_exp2f(fmaf(s[qt][c][r], K2, mk));
            #pragma unroll
            for (int kg = 0; kg < 2; ++kg) {
                u32x4 pw;
                pw[0] = __builtin_bit_cast(unsigned, __builtin_amdgcn_cvt_pkrtz(s[qt][2 * kg][0], s[qt][2 * kg][1]));
                pw[1] = __builtin_bit_cast(unsigned, __builtin_amdgcn_cvt_pkrtz(s[qt][2 * kg][2], s[qt][2 * kg][3]));
                pw[2] = __builtin_bit_cast(unsigned, __builtin_amdgcn_cvt_pkrtz(s[qt][2 * kg + 1][0], s[qt][2 * kg + 1][1]));
                pw[3] = __builtin_bit_cast(unsigned, __builtin_amdgcn_cvt_pkrtz(s[qt][2 * kg + 1][2], s[qt][2 * kg + 1][3]));
                pfrag[qt][kg] = __builtin_bit_cast(f16x8, pw);
            }
        }

        // ---- PV (K=32) + ones row-sums; V frags shared across qt
        lsum[0] = __builtin_amdgcn_mfma_f32_16x16x32_f16(ones8, pfrag[0][0], lsum[0], 0, 0, 0);
        lsum[1] = __builtin_amdgcn_mfma_f32_16x16x32_f16(ones8, pfrag[1][0], lsum[1], 0, 0, 0);
        #pragma unroll
        for (int c2 = 0; c2 < 4; ++c2) {
            f16x8 vf = *reinterpret_cast<const f16x8*>(&smem[vb0 + c2 * 4096]);
            oacc[0][c2] = __builtin_amdgcn_mfma_f32_16x16x32_f16(vf, pfrag[0][0], oacc[0][c2], 0, 0, 0);
            oacc[1][c2] = __builtin_amdgcn_mfma_f32_16x16x32_f16(vf, pfrag[1][0], oacc[1][c2], 0, 0, 0);
        }
        lsum[0] = __builtin_amdgcn_mfma_f32_16x16x32_f16(ones8, pfrag[0][1], lsum[0], 0, 0, 0);
        lsum[1] = __builtin_amdgcn_mfma_f32_16x16x32_f16(ones8, pfrag[1][1], lsum[1], 0, 0, 0);
        #pragma unroll
        for (int c2 = 0; c2 < 4; ++c2) {
            f16x8 vf = *reinterpret_cast<const f16x8*>(&smem[vb1 + c2 * 4096]);
            oacc[0][c2] = __builtin_amdgcn_mfma_f32_16x16x32_f16(vf, pfrag[0][1], oacc[0][c2], 0, 0, 0);
            oacc[1][c2] = __builtin_amdgcn_mfma_f32_16x16x32_f16(vf, pfrag[1][1], oacc[1][c2], 0, 0, 0);
        }

        __syncthreads();
        kb0 ^= 32768; kb1 ^= 32768; vb0 ^= 32768; vb1 ^= 32768;
        nstK ^= 32768; nstV ^= 32768;
    }

    // ---- key-half merge via LDS (flash-merge), then -rope epilogue
    if (kh == 1) {
        #pragma unroll
        for (int qt = 0; qt < 2; ++qt) {
            float* Of = (float*)smem + (qg * 2 + qt) * 1120;
            #pragma unroll
            for (int c2 = 0; c2 < 4; ++c2)
                *reinterpret_cast<f32x4*>(&Of[lx * 68 + c2 * 16 + g * 4]) = oacc[qt][c2];
            if (g == 0) {
                Of[1088 + lx] = mrow[qt];
                Of[1104 + lx] = lsum[qt][0];
            }
        }
    }
    __syncthreads();
    if (kh == 0) {
        #pragma unroll
        for (int qt = 0; qt < 2; ++qt) {
            float* Of = (float*)smem + (qg * 2 + qt) * 1120;
            float m_hi = Of[1088 + lx];
            float l_hi = Of[1104 + lx];
            float M = fmaxf(mrow[qt], m_hi);
            float a  = __builtin_amdgcn_exp2f((mrow[qt] - M) * K2);
            float bb = __builtin_amdgcn_exp2f((m_hi - M) * K2);
            float inv = 1.0f / (a * lsum[qt][0] + bb * l_hi);
            const int q = q0 + qg * 32 + qt * 16 + lx;
            unsigned short* drow = Y + ((size_t)b * SEQLEN + q) * DIMSZ + h * HDIM;
            #pragma unroll
            for (int c2 = 0; c2 < 4; ++c2) {
                f32x4 ohi = *reinterpret_cast<const f32x4*>(&Of[lx * 68 + c2 * 16 + g * 4]);
                const float* tab = ((c2 < 2) ? ropeC : ropeS) + (size_t)q * 32;
                unsigned short lo16[2], hi16[2];
                #pragma unroll
                for (int rp = 0; rp < 2; ++rp) {
                    int d = c2 * 16 + g * 4 + 2 * rp;        // even d
                    float v0 = (a * oacc[qt][c2][2 * rp]     + bb * ohi[2 * rp])     * inv;
                    float v1 = (a * oacc[qt][c2][2 * rp + 1] + bb * ohi[2 * rp + 1]) * inv;
                    float Rd = tab[d & 31], Rn = tab[(d & 31) + 1];
                    lo16[rp] = f16u(-(v0 * Rd - v1 * Rn));
                    hi16[rp] = f16u(-(v0 * Rn + v1 * Rd));
                }
                int p = c2 * 8 + g * 2;                       // even column
                *reinterpret_cast<unsigned*>(&drow[p])      = (unsigned)lo16[0] | ((unsigned)lo16[1] << 16);
                *reinterpret_cast<unsigned*>(&drow[p + 32]) = (unsigned)hi16[0] | ((unsigned)hi16[1] << 16);
            }
        }
    }
}

// ---------------------------------------------------------------------------
// Out GEMM: out[4096 x 1024] = Y16 @ Wo16^T + bo (f32 out).
// ---------------------------------------------------------------------------
__global__ __launch_bounds__(512, 4) void out_gemm_kernel(
    const unsigned short* __restrict__ A, const unsigned short* __restrict__ B,
    const float* __restrict__ bias, float* __restrict__ Out)
{
    __shared__ __align__(16) unsigned char smem[65536];
    const int tid = threadIdx.x;
    const int w = tid >> 6, l = tid & 63;
    const int g = l >> 4, lx = l & 15;
    const int wr = w >> 2, wc = w & 3;
    const int row0 = blockIdx.y * 128;
    const int col0 = blockIdx.x * 128;
    const unsigned short* Ab = A + (size_t)row0 * DIMSZ;
    const unsigned short* Bb = B + (size_t)col0 * DIMSZ;

    const int sr = tid >> 3;
    const int sc = tid & 7;
    const int ssw = sc ^ (sr & 7);
    const size_t sAoff0 = (size_t)sr * DIMSZ + ssw * 8;
    const size_t sAoff1 = (size_t)(64 + sr) * DIMSZ + ssw * 8;

    f32x4 acc[4][2] = {};
    async_copy16(Ab + sAoff0, smem + tid * 16);
    async_copy16(Ab + sAoff1, smem + 8192 + tid * 16);
    async_copy16(Bb + sAoff0, smem + 16384 + tid * 16);
    async_copy16(Bb + sAoff1, smem + 16384 + 8192 + tid * 16);
    __syncthreads();

    int buf = 0;
    for (int k0 = 0; k0 < DIMSZ; k0 += 64) {
        if (k0 + 64 < DIMSZ) {
            const int nb = (buf ^ 1) * 32768;
            async_copy16(Ab + sAoff0 + k0 + 64, smem + nb + tid * 16);
            async_copy16(Ab + sAoff1 + k0 + 64, smem + nb + 8192 + tid * 16);
            async_copy16(Bb + sAoff0 + k0 + 64, smem + nb + 16384 + tid * 16);
            async_copy16(Bb + sAoff1 + k0 + 64, smem + nb + 16384 + 8192 + tid * 16);
        }
        const int ab = buf * 32768, bb2 = ab + 16384;
        #pragma unroll
        for (int ks = 0; ks < 2; ++ks) {
            f16x8 af[4], bf[2];
            #pragma unroll
            for (int m = 0; m < 4; ++m) {
                int r = wr * 64 + m * 16 + lx;
                af[m] = *reinterpret_cast<const f16x8*>(
                    &smem[ab + r * 128 + ((ks * 64 + g * 16) ^ ((r & 7) << 4))]);
            }
            #pragma unroll
            for (int n = 0; n < 2; ++n) {
                int r = wc * 32 + n * 16 + lx;
                bf[n] = *reinterpret_cast<const f16x8*>(
                    &smem[bb2 + r * 128 + ((ks * 64 + g * 16) ^ ((r & 7) << 4))]);
            }
            #pragma unroll
            for (int m = 0; m < 4; ++m)
                #pragma unroll
                for (int n = 0; n < 2; ++n)
                    acc[m][n] = __builtin_amdgcn_mfma_f32_16x16x32_f16(af[m], bf[n], acc[m][n], 0, 0, 0);
        }
        __syncthreads();
        buf ^= 1;
    }

    const int cb0 = col0 + wc * 32;
    float bsv[2];
    #pragma unroll
    for (int n = 0; n < 2; ++n) bsv[n] = bias[cb0 + n * 16 + lx];
    #pragma unroll
    for (int m = 0; m < 4; ++m) {
        int rbase = row0 + wr * 64 + m * 16 + g * 4;
        #pragma unroll
        for (int r2 = 0; r2 < 4; ++r2) {
            float* orow = Out + (size_t)(rbase + r2) * DIMSZ + cb0;
            #pragma unroll
            for (int n = 0; n < 2; ++n)
                orow[n * 16 + lx] = acc[m][n][r2] + bsv[n];
        }
    }
}

extern "C" void kernel_launch(void* const* d_in, const int* in_sizes, int n_in,
                              void* d_out, int out_size, void* d_ws, size_t ws_size,
                              hipStream_t stream) {
    const float* x  = (const float*)d_in[0];
    const float* Wq = (const float*)d_in[1];
    const float* bq = (const float*)d_in[2];
    const float* Wk = (const float*)d_in[3];
    const float* bk = (const float*)d_in[4];
    const float* Wv = (const float*)d_in[5];
    const float* bv = (const float*)d_in[6];
    const float* Wo = (const float*)d_in[7];
    const float* bo = (const float*)d_in[8];
    float* out = (float*)d_out;

    char* ws = (char*)d_ws;
    unsigned short* x16    = (unsigned short*)(ws);
    unsigned short* Wqkv16 = (unsigned short*)(ws + 8388608);
    unsigned short* Wo16   = (unsigned short*)(ws + 14680064);
    float* biasqkv         = (float*)(ws + 16777216);
    float* ropeC           = (float*)(ws + 16793600);
    float* ropeS           = (float*)(ws + 17055744);
    unsigned short* QKVw   = (unsigned short*)(ws + 17825792);
    unsigned short* Yw     = (unsigned short*)(ws + 42991616);

    prep_kernel<<<dim3(2048), dim3(256), 0, stream>>>(x, Wq, Wk, Wv, Wo, bq, bk, bv,
                                                x16, Wqkv16, Wo16, biasqkv, ropeC, ropeS);
    qkv_gemm_kernel<<<dim3(24, 32), dim3(512), 0, stream>>>(x16, Wqkv16, biasqkv, ropeC, ropeS, QKVw);
    attn_mfma_kernel<<<dim3(512), dim3(512), 0, stream>>>(QKVw, ropeC, ropeS, Yw);
    out_gemm_kernel<<<dim3(8, 32), dim3(512), 0, stream>>>(Yw, Wo16, bo, out);
}

// Round 19
// 116.788 us; speedup vs baseline: 1.1648x; 1.0051x over previous
//
#include <hip/hip_runtime.h>
#include <hip/hip_bf16.h>
#include <math.h>

#define NHEADS 16
#define HDIM   64
#define BATCH  2
#define SEQLEN 2048
#define DIMSZ  1024

typedef _Float16 f16x8 __attribute__((ext_vector_type(8)));
typedef float    f32x4 __attribute__((ext_vector_type(4)));
typedef unsigned short u16x8 __attribute__((ext_vector_type(8)));
typedef unsigned int   u32x4 __attribute__((ext_vector_type(4)));

__device__ __forceinline__ float rope_theta(int c) {
    int i = c & 31;
    return (float)pow(10000.0, -(double)i / 32.0);
}
__device__ __forceinline__ unsigned short f16u(float f) {
    _Float16 h = (_Float16)f;
    return *reinterpret_cast<unsigned short*>(&h);
}
__device__ __forceinline__ void async_copy16(const void* gsrc, void* lds) {
    __builtin_amdgcn_global_load_lds(
        (const __attribute__((address_space(1))) unsigned int*)gsrc,
        (__attribute__((address_space(3))) unsigned int*)lds, 16, 0, 0);
}

// ---------------------------------------------------------------------------
// prep: f32->f16 conversions (x, Wq|Wk|Wv concat, Wo), bias concat, rope tables
// ---------------------------------------------------------------------------
__global__ __launch_bounds__(256) void prep_kernel(
    const float* __restrict__ x, const float* __restrict__ Wq,
    const float* __restrict__ Wk, const float* __restrict__ Wv,
    const float* __restrict__ Wo, const float* __restrict__ bq,
    const float* __restrict__ bk, const float* __restrict__ bv,
    unsigned short* __restrict__ x16, unsigned short* __restrict__ Wqkv16,
    unsigned short* __restrict__ Wo16, float* __restrict__ biasqkv,
    float* __restrict__ ropeC, float* __restrict__ ropeS)
{
    const int NV = (4194304 + 4 * 1048576) / 8;   // 1,048,576 vec8 chunks
    int gid = blockIdx.x * 256 + threadIdx.x;
    for (int i = gid; i < NV; i += gridDim.x * 256) {
        long e = (long)i * 8;
        const float* src; unsigned short* dst; long off;
        if (e < 4194304)      { src = x;  dst = x16;              off = e; }
        else if (e < 5242880) { src = Wq; dst = Wqkv16;           off = e - 4194304; }
        else if (e < 6291456) { src = Wk; dst = Wqkv16 + 1048576; off = e - 5242880; }
        else if (e < 7340032) { src = Wv; dst = Wqkv16 + 2097152; off = e - 6291456; }
        else                  { src = Wo; dst = Wo16;             off = e - 7340032; }
        float4 v0 = *reinterpret_cast<const float4*>(src + off);
        float4 v1 = *reinterpret_cast<const float4*>(src + off + 4);
        u16x8 o;
        o[0] = f16u(v0.x); o[1] = f16u(v0.y); o[2] = f16u(v0.z); o[3] = f16u(v0.w);
        o[4] = f16u(v1.x); o[5] = f16u(v1.y); o[6] = f16u(v1.z); o[7] = f16u(v1.w);
        *reinterpret_cast<u16x8*>(dst + off) = o;
    }
    if (gid < 65536) {
        int npos = gid >> 5, j = gid & 31;
        float f = (float)npos * rope_theta(j);
        ropeC[gid] = cosf(f);
        ropeS[gid] = sinf(f);
    }
    if (gid < 3072) {
        biasqkv[gid] = gid < 1024 ? bq[gid] : (gid < 2048 ? bk[gid - 1024] : bv[gid - 2048]);
    }
}

// ---------------------------------------------------------------------------
// Fused QKV GEMM + bias + (non-standard) rope. 512 thr / 8 waves (64x32
// sub-tiles), double-buffered swizzled LDS, 1 barrier per K-step.
// XCD-chunked 1D grid (768 blocks): 96 consecutive tiles per XCD -> A/B
// panels stay L2-local.
// ---------------------------------------------------------------------------
__global__ __launch_bounds__(512, 4) void qkv_gemm_kernel(
    const unsigned short* __restrict__ A, const unsigned short* __restrict__ B,
    const float* __restrict__ bias, const float* __restrict__ ropeC,
    const float* __restrict__ ropeS, unsigned short* __restrict__ QKV)
{
    __shared__ __align__(16) unsigned char smem[65536];
    const int tid = threadIdx.x;
    const int w = tid >> 6, l = tid & 63;
    const int g = l >> 4, lx = l & 15;
    const int wr = w >> 2, wc = w & 3;        // 2x4 wave grid: 64x32 subtile
    const int fb  = blockIdx.x;
    const int fbp = (fb & 7) * 96 + (fb >> 3);   // bijective: 768 = 8*96
    const int bx  = fbp % 24, by = fbp / 24;
    const int row0 = by * 128;
    const int col0 = bx * 128;
    const unsigned short* Ab = A + (size_t)row0 * DIMSZ;
    const unsigned short* Bb = B + (size_t)col0 * DIMSZ;

    const int sr = tid >> 3;                   // 0..63
    const int sc = tid & 7;
    const int ssw = sc ^ (sr & 7);
    const size_t sAoff0 = (size_t)sr * DIMSZ + ssw * 8;
    const size_t sAoff1 = (size_t)(64 + sr) * DIMSZ + ssw * 8;

    f32x4 acc[4][2] = {};
    async_copy16(Ab + sAoff0, smem + tid * 16);
    async_copy16(Ab + sAoff1, smem + 8192 + tid * 16);
    async_copy16(Bb + sAoff0, smem + 16384 + tid * 16);
    async_copy16(Bb + sAoff1, smem + 16384 + 8192 + tid * 16);
    __syncthreads();

    int buf = 0;
    for (int k0 = 0; k0 < DIMSZ; k0 += 64) {
        if (k0 + 64 < DIMSZ) {
            const int nb = (buf ^ 1) * 32768;
            async_copy16(Ab + sAoff0 + k0 + 64, smem + nb + tid * 16);
            async_copy16(Ab + sAoff1 + k0 + 64, smem + nb + 8192 + tid * 16);
            async_copy16(Bb + sAoff0 + k0 + 64, smem + nb + 16384 + tid * 16);
            async_copy16(Bb + sAoff1 + k0 + 64, smem + nb + 16384 + 8192 + tid * 16);
        }
        const int ab = buf * 32768, bb2 = ab + 16384;
        #pragma unroll
        for (int ks = 0; ks < 2; ++ks) {
            f16x8 af[4], bf[2];
            #pragma unroll
            for (int m = 0; m < 4; ++m) {
                int r = wr * 64 + m * 16 + lx;
                af[m] = *reinterpret_cast<const f16x8*>(
                    &smem[ab + r * 128 + ((ks * 64 + g * 16) ^ ((r & 7) << 4))]);
            }
            #pragma unroll
            for (int n = 0; n < 2; ++n) {
                int r = wc * 32 + n * 16 + lx;
                bf[n] = *reinterpret_cast<const f16x8*>(
                    &smem[bb2 + r * 128 + ((ks * 64 + g * 16) ^ ((r & 7) << 4))]);
            }
            #pragma unroll
            for (int m = 0; m < 4; ++m)
                #pragma unroll
                for (int n = 0; n < 2; ++n)
                    acc[m][n] = __builtin_amdgcn_mfma_f32_16x16x32_f16(af[m], bf[n], acc[m][n], 0, 0, 0);
        }
        __syncthreads();
        buf ^= 1;
    }

    const int proj = col0 >> 10;               // block-uniform
    const int cin128 = (col0 & 1023);
    float bsv[2];
    #pragma unroll
    for (int n = 0; n < 2; ++n) bsv[n] = bias[col0 + wc * 32 + n * 16 + lx];

    if (proj == 2) {
        _Float16* T = (_Float16*)smem;   // [128][136]
        #pragma unroll
        for (int m = 0; m < 4; ++m) {
            int rl0 = wr * 64 + m * 16 + g * 4;
            #pragma unroll
            for (int r2 = 0; r2 < 4; ++r2) {
                int rlocal = rl0 + r2;
                int npos = (row0 + rlocal) & (SEQLEN - 1);
                const float* rcp = ropeC + npos * 32;
                const float* rsp = ropeS + npos * 32;
                #pragma unroll
                for (int n = 0; n < 2; ++n) {
                    float v = acc[m][n][r2] + bsv[n];
                    float o = __shfl_xor(v, 1);
                    int dcol = wc * 32 + n * 16 + lx;
                    int c = dcol & 63;
                    const float* tab = (c < 32) ? rcp : rsp;
                    float Rd = tab[c & 31];
                    float Rp = tab[(c & 31) ^ 1];
                    float y; int outc;
                    if (c & 1) { y = o * Rd + v * Rp; outc = (c >> 1) + 32; }
                    else       { y = v * Rd - o * Rp; outc = c >> 1; }
                    T[((dcol >> 6) * 64 + outc) * 136 + rlocal] = (_Float16)y;
                }
            }
        }
        __syncthreads();
        int b = row0 >> 11, npos0 = row0 & (SEQLEN - 1);
        int hd0 = cin128 >> 6;
        int trow = tid >> 2;
        int cbase = (tid & 3) * 32;
        int head = hd0 + (trow >> 6);
        int outd = trow & 63;
        unsigned short* vdst = QKV + 8388608 +
            (((size_t)b * NHEADS + head) * HDIM + outd) * SEQLEN + npos0 + cbase;
        #pragma unroll
        for (int i2 = 0; i2 < 4; ++i2) {
            f16x8 val = *reinterpret_cast<const f16x8*>(&T[trow * 136 + cbase + i2 * 8]);
            *reinterpret_cast<f16x8*>(vdst + i2 * 8) = val;
        }
    } else {
        #pragma unroll
        for (int m = 0; m < 4; ++m) {
            int rbase = row0 + wr * 64 + m * 16 + g * 4;
            #pragma unroll
            for (int r2 = 0; r2 < 4; ++r2) {
                int rglob = rbase + r2;
                int b = rglob >> 11, npos = rglob & (SEQLEN - 1);
                const float* rcp = ropeC + npos * 32;
                const float* rsp = ropeS + npos * 32;
                #pragma unroll
                for (int n = 0; n < 2; ++n) {
                    float v = acc[m][n][r2] + bsv[n];
                    float o = __shfl_xor(v, 1);
                    int hd = (cin128 + wc * 32 + n * 16) >> 6;
                    int c = ((wc * 32 + n * 16) & 63) + lx;
                    const float* tab = (c < 32) ? rcp : rsp;
                    float Rd = tab[c & 31];
                    float Rp = tab[(c & 31) ^ 1];
                    float y; int outc;
                    if (c & 1) { y = o * Rd + v * Rp; outc = (c >> 1) + 32; }
                    else       { y = v * Rd - o * Rp; outc = c >> 1; }
                    unsigned short* Orow = QKV +
                        ((((size_t)proj * BATCH + b) * NHEADS + hd) * SEQLEN + npos) * HDIM;
                    Orow[outc] = f16u(y);
                }
            }
        }
    }
}

// ---------------------------------------------------------------------------
// MFMA flash attention (f16). 128-q blocks x 128-key tiles (16 barriers).
// 8 waves = 4 q-groups (32 q: qt=0,1) x 2 key-halves. Permuted-K staging so
// packed P = K=32 B-frag (no shfl). V^T 256B rows: linear dest, inv-XOR src.
// ---------------------------------------------------------------------------
__global__ __launch_bounds__(512, 4) void attn_mfma_kernel(
    const unsigned short* __restrict__ QKV, const float* __restrict__ ropeC,
    const float* __restrict__ ropeS, unsigned short* __restrict__ Y)
{
    __shared__ __align__(16) unsigned char smem[65536];
    const int tid = threadIdx.x;
    const int w   = tid >> 6;
    const int l   = tid & 63;
    const int g   = l >> 4;
    const int lx  = l & 15;
    const int qg  = w & 3;      // q-group: 32 q per wave
    const int kh  = w >> 2;     // key half: 64 keys of each 128-key tile
    const int fb  = blockIdx.x;
    const int xcd = fb & 7, jj = fb >> 3;
    const int bh  = xcd * 4 + (jj & 3);       // 4 bh per XCD -> K/V L2-local
    const int b   = bh >> 4;
    const int h   = bh & 15;
    const int q0  = (jj >> 2) * 128;

    const unsigned short* Qb  = QKV + (size_t)bh * SEQLEN * HDIM;
    const unsigned short* Kb  = QKV + 4194304 + (size_t)bh * SEQLEN * HDIM;
    const unsigned short* Vtb = QKV + 8388608 + (size_t)bh * SEQLEN * HDIM;  // (d,n)

    f16x8 qf[2][2];
    #pragma unroll
    for (int qt = 0; qt < 2; ++qt) {
        const unsigned short* src = Qb + (size_t)(q0 + qg * 32 + qt * 16 + lx) * HDIM + g * 8;
        qf[qt][0] = *reinterpret_cast<const f16x8*>(src);
        qf[qt][1] = *reinterpret_cast<const f16x8*>(src + 32);
    }
    f16x8 ones8;
    #pragma unroll
    for (int i = 0; i < 8; ++i) ones8[i] = (_Float16)1.0f;

    const float K2 = 0.18033688011112043f;    // 0.125 * log2(e)
    f32x4 oacc[2][4] = {};
    f32x4 lsum[2] = {};
    float mrow[2] = {-1e30f, -1e30f};

    const int srow = tid >> 3;                 // 0..63
    const int c8   = tid & 7;
    const int sch  = c8 ^ (srow & 7);
    const int kperm = (srow & 32) + (((srow >> 2) & 3) << 3) + (((srow >> 4) & 1) << 2) + (srow & 3);
    const unsigned short* Kp = Kb + (size_t)kperm * HDIM + sch * 8;
    const int vrow = tid >> 4;                 // 0..31
    const int vsw  = ((tid & 15) ^ (vrow & 15)) * 8;
    const unsigned short* Vp0 = Vtb + (size_t)vrow * SEQLEN + vsw;
    const unsigned short* Vp1 = Vtb + (size_t)(32 + vrow) * SEQLEN + vsw;

    async_copy16(Kp, smem + tid * 16);
    async_copy16(Kp + 64 * HDIM, smem + 8192 + tid * 16);
    async_copy16(Vp0, smem + 16384 + tid * 16);
    async_copy16(Vp1, smem + 16384 + 8192 + tid * 16);
    Kp += 128 * HDIM; Vp0 += 128; Vp1 += 128;
    __syncthreads();

    const int sw = (lx & 7) << 4;
    unsigned kb0 = (kh * 64 + lx) * 128 + ((g * 16) ^ sw);
    unsigned kb1 = (kh * 64 + lx) * 128 + ((64 + g * 16) ^ sw);
    unsigned vbr = 16384 + lx * 256;
    unsigned vb0 = vbr + ((kh * 128 + g * 16) ^ (lx << 4));
    unsigned vb1 = vbr + ((kh * 128 + 64 + g * 16) ^ (lx << 4));
    unsigned nstK = 32768 + tid * 16;
    unsigned nstV = 32768 + 16384 + tid * 16;

    for (int kt = 0; kt < 16; ++kt) {
        if (kt < 15) {
            async_copy16(Kp, smem + nstK);
            async_copy16(Kp + 64 * HDIM, smem + nstK + 8192);
            async_copy16(Vp0, smem + nstV);
            async_copy16(Vp1, smem + nstV + 8192);
            Kp += 128 * HDIM; Vp0 += 128; Vp1 += 128;
        }

        f32x4 s[2][4] = {};
        #pragma unroll
        for (int c = 0; c < 4; ++c) {
            f16x8 kf0 = *reinterpret_cast<const f16x8*>(&smem[kb0 + c * 2048]);
            f16x8 kf1 = *reinterpret_cast<const f16x8*>(&smem[kb1 + c * 2048]);
            s[0][c] = __builtin_amdgcn_mfma_f32_16x16x32_f16(kf0, qf[0][0], s[0][c], 0, 0, 0);
            s[0][c] = __builtin_amdgcn_mfma_f32_16x16x32_f16(kf1, qf[0][1], s[0][c], 0, 0, 0);
            s[1][c] = __builtin_amdgcn_mfma_f32_16x16x32_f16(kf0, qf[1][0], s[1][c], 0, 0, 0);
            s[1][c] = __builtin_amdgcn_mfma_f32_16x16x32_f16(kf1, qf[1][1], s[1][c], 0, 0, 0);
        }

        f16x8 pfrag[2][2];
        #pragma unroll
        for (int qt = 0; qt < 2; ++qt) {
            float lmax = s[qt][0][0];
            #pragma unroll
            for (int c = 0; c < 4; ++c)
                #pragma unroll
                for (int r = 0; r < 4; ++r) lmax = fmaxf(lmax, s[qt][c][r]);
            bool ok = (lmax <= mrow[qt] + 64.f);
            if (!__all((int)ok)) {
                float m2 = fmaxf(lmax, __shfl_xor(lmax, 16));
                m2 = fmaxf(m2, __shfl_xor(m2, 32));
                float mnew = fmaxf(mrow[qt], m2);
                float sc = __builtin_amdgcn_exp2f((mrow[qt] - mnew) * K2);
                mrow[qt] = mnew;
                lsum[qt] *= sc;
                #pragma unroll
                for (int c2 = 0; c2 < 4; ++c2) oacc[qt][c2] *= sc;
            }
            float mk = -mrow[qt] * K2;
            #pragma unroll
            for (int c = 0; c < 4; ++c)
                #pragma unroll
                for (int r = 0; r < 4; ++r)
                    s[qt][c][r] = __builtin_amdgcn_exp2f(fmaf(s[qt][c][r], K2, mk));
            #pragma unroll
            for (int kg = 0; kg < 2; ++kg) {
                u32x4 pw;
                pw[0] = __builtin_bit_cast(unsigned, __builtin_amdgcn_cvt_pkrtz(s[qt][2 * kg][0], s[qt][2 * kg][1]));
                pw[1] = __builtin_bit_cast(unsigned, __builtin_amdgcn_cvt_pkrtz(s[qt][2 * kg][2], s[qt][2 * kg][3]));
                pw[2] = __builtin_bit_cast(unsigned, __builtin_amdgcn_cvt_pkrtz(s[qt][2 * kg + 1][0], s[qt][2 * kg + 1][1]));
                pw[3] = __builtin_bit_cast(unsigned, __builtin_amdgcn_cvt_pkrtz(s[qt][2 * kg + 1][2], s[qt][2 * kg + 1][3]));
                pfrag[qt][kg] = __builtin_bit_cast(f16x8, pw);
            }
        }

        lsum[0] = __builtin_amdgcn_mfma_f32_16x16x32_f16(ones8, pfrag[0][0], lsum[0], 0, 0, 0);
        lsum[1] = __builtin_amdgcn_mfma_f32_16x16x32_f16(ones8, pfrag[1][0], lsum[1], 0, 0, 0);
        #pragma unroll
        for (int c2 = 0; c2 < 4; ++c2) {
            f16x8 vf = *reinterpret_cast<const f16x8*>(&smem[vb0 + c2 * 4096]);
            oacc[0][c2] = __builtin_amdgcn_mfma_f32_16x16x32_f16(vf, pfrag[0][0], oacc[0][c2], 0, 0, 0);
            oacc[1][c2] = __builtin_amdgcn_mfma_f32_16x16x32_f16(vf, pfrag[1][0], oacc[1][c2], 0, 0, 0);
        }
        lsum[0] = __builtin_amdgcn_mfma_f32_16x16x32_f16(ones8, pfrag[0][1], lsum[0], 0, 0, 0);
        lsum[1] = __builtin_amdgcn_mfma_f32_16x16x32_f16(ones8, pfrag[1][1], lsum[1], 0, 0, 0);
        #pragma unroll
        for (int c2 = 0; c2 < 4; ++c2) {
            f16x8 vf = *reinterpret_cast<const f16x8*>(&smem[vb1 + c2 * 4096]);
            oacc[0][c2] = __builtin_amdgcn_mfma_f32_16x16x32_f16(vf, pfrag[0][1], oacc[0][c2], 0, 0, 0);
            oacc[1][c2] = __builtin_amdgcn_mfma_f32_16x16x32_f16(vf, pfrag[1][1], oacc[1][c2], 0, 0, 0);
        }

        __syncthreads();
        kb0 ^= 32768; kb1 ^= 32768; vb0 ^= 32768; vb1 ^= 32768;
        nstK ^= 32768; nstV ^= 32768;
    }

    // ---- key-half merge via LDS (flash-merge), then -rope epilogue
    if (kh == 1) {
        #pragma unroll
        for (int qt = 0; qt < 2; ++qt) {
            float* Of = (float*)smem + (qg * 2 + qt) * 1120;
            #pragma unroll
            for (int c2 = 0; c2 < 4; ++c2)
                *reinterpret_cast<f32x4*>(&Of[lx * 68 + c2 * 16 + g * 4]) = oacc[qt][c2];
            if (g == 0) {
                Of[1088 + lx] = mrow[qt];
                Of[1104 + lx] = lsum[qt][0];
            }
        }
    }
    __syncthreads();
    if (kh == 0) {
        #pragma unroll
        for (int qt = 0; qt < 2; ++qt) {
            float* Of = (float*)smem + (qg * 2 + qt) * 1120;
            float m_hi = Of[1088 + lx];
            float l_hi = Of[1104 + lx];
            float M = fmaxf(mrow[qt], m_hi);
            float a  = __builtin_amdgcn_exp2f((mrow[qt] - M) * K2);
            float bb = __builtin_amdgcn_exp2f((m_hi - M) * K2);
            float inv = 1.0f / (a * lsum[qt][0] + bb * l_hi);
            const int q = q0 + qg * 32 + qt * 16 + lx;
            unsigned short* drow = Y + ((size_t)b * SEQLEN + q) * DIMSZ + h * HDIM;
            #pragma unroll
            for (int c2 = 0; c2 < 4; ++c2) {
                f32x4 ohi = *reinterpret_cast<const f32x4*>(&Of[lx * 68 + c2 * 16 + g * 4]);
                const float* tab = ((c2 < 2) ? ropeC : ropeS) + (size_t)q * 32;
                unsigned short lo16[2], hi16[2];
                #pragma unroll
                for (int rp = 0; rp < 2; ++rp) {
                    int d = c2 * 16 + g * 4 + 2 * rp;        // even d
                    float v0 = (a * oacc[qt][c2][2 * rp]     + bb * ohi[2 * rp])     * inv;
                    float v1 = (a * oacc[qt][c2][2 * rp + 1] + bb * ohi[2 * rp + 1]) * inv;
                    float Rd = tab[d & 31], Rn = tab[(d & 31) + 1];
                    lo16[rp] = f16u(-(v0 * Rd - v1 * Rn));
                    hi16[rp] = f16u(-(v0 * Rn + v1 * Rd));
                }
                int p = c2 * 8 + g * 2;                       // even column
                *reinterpret_cast<unsigned*>(&drow[p])      = (unsigned)lo16[0] | ((unsigned)lo16[1] << 16);
                *reinterpret_cast<unsigned*>(&drow[p + 32]) = (unsigned)hi16[0] | ((unsigned)hi16[1] << 16);
            }
        }
    }
}

// ---------------------------------------------------------------------------
// Out GEMM: out[4096 x 1024] = Y16 @ Wo16^T + bo (f32 out).
// XCD-chunked 1D grid (256 blocks = 8 x 32).
// ---------------------------------------------------------------------------
__global__ __launch_bounds__(512, 4) void out_gemm_kernel(
    const unsigned short* __restrict__ A, const unsigned short* __restrict__ B,
    const float* __restrict__ bias, float* __restrict__ Out)
{
    __shared__ __align__(16) unsigned char smem[65536];
    const int tid = threadIdx.x;
    const int w = tid >> 6, l = tid & 63;
    const int g = l >> 4, lx = l & 15;
    const int wr = w >> 2, wc = w & 3;
    const int fb  = blockIdx.x;
    const int fbp = (fb & 7) * 32 + (fb >> 3);   // bijective: 256 = 8*32
    const int bx  = fbp & 7, by = fbp >> 3;
    const int row0 = by * 128;
    const int col0 = bx * 128;
    const unsigned short* Ab = A + (size_t)row0 * DIMSZ;
    const unsigned short* Bb = B + (size_t)col0 * DIMSZ;

    const int sr = tid >> 3;
    const int sc = tid & 7;
    const int ssw = sc ^ (sr & 7);
    const size_t sAoff0 = (size_t)sr * DIMSZ + ssw * 8;
    const size_t sAoff1 = (size_t)(64 + sr) * DIMSZ + ssw * 8;

    f32x4 acc[4][2] = {};
    async_copy16(Ab + sAoff0, smem + tid * 16);
    async_copy16(Ab + sAoff1, smem + 8192 + tid * 16);
    async_copy16(Bb + sAoff0, smem + 16384 + tid * 16);
    async_copy16(Bb + sAoff1, smem + 16384 + 8192 + tid * 16);
    __syncthreads();

    int buf = 0;
    for (int k0 = 0; k0 < DIMSZ; k0 += 64) {
        if (k0 + 64 < DIMSZ) {
            const int nb = (buf ^ 1) * 32768;
            async_copy16(Ab + sAoff0 + k0 + 64, smem + nb + tid * 16);
            async_copy16(Ab + sAoff1 + k0 + 64, smem + nb + 8192 + tid * 16);
            async_copy16(Bb + sAoff0 + k0 + 64, smem + nb + 16384 + tid * 16);
            async_copy16(Bb + sAoff1 + k0 + 64, smem + nb + 16384 + 8192 + tid * 16);
        }
        const int ab = buf * 32768, bb2 = ab + 16384;
        #pragma unroll
        for (int ks = 0; ks < 2; ++ks) {
            f16x8 af[4], bf[2];
            #pragma unroll
            for (int m = 0; m < 4; ++m) {
                int r = wr * 64 + m * 16 + lx;
                af[m] = *reinterpret_cast<const f16x8*>(
                    &smem[ab + r * 128 + ((ks * 64 + g * 16) ^ ((r & 7) << 4))]);
            }
            #pragma unroll
            for (int n = 0; n < 2; ++n) {
                int r = wc * 32 + n * 16 + lx;
                bf[n] = *reinterpret_cast<const f16x8*>(
                    &smem[bb2 + r * 128 + ((ks * 64 + g * 16) ^ ((r & 7) << 4))]);
            }
            #pragma unroll
            for (int m = 0; m < 4; ++m)
                #pragma unroll
                for (int n = 0; n < 2; ++n)
                    acc[m][n] = __builtin_amdgcn_mfma_f32_16x16x32_f16(af[m], bf[n], acc[m][n], 0, 0, 0);
        }
        __syncthreads();
        buf ^= 1;
    }

    const int cb0 = col0 + wc * 32;
    float bsv[2];
    #pragma unroll
    for (int n = 0; n < 2; ++n) bsv[n] = bias[cb0 + n * 16 + lx];
    #pragma unroll
    for (int m = 0; m < 4; ++m) {
        int rbase = row0 + wr * 64 + m * 16 + g * 4;
        #pragma unroll
        for (int r2 = 0; r2 < 4; ++r2) {
            float* orow = Out + (size_t)(rbase + r2) * DIMSZ + cb0;
            #pragma unroll
            for (int n = 0; n < 2; ++n)
                orow[n * 16 + lx] = acc[m][n][r2] + bsv[n];
        }
    }
}

extern "C" void kernel_launch(void* const* d_in, const int* in_sizes, int n_in,
                              void* d_out, int out_size, void* d_ws, size_t ws_size,
                              hipStream_t stream) {
    const float* x  = (const float*)d_in[0];
    const float* Wq = (const float*)d_in[1];
    const float* bq = (const float*)d_in[2];
    const float* Wk = (const float*)d_in[3];
    const float* bk = (const float*)d_in[4];
    const float* Wv = (const float*)d_in[5];
    const float* bv = (const float*)d_in[6];
    const float* Wo = (const float*)d_in[7];
    const float* bo = (const float*)d_in[8];
    float* out = (float*)d_out;

    char* ws = (char*)d_ws;
    unsigned short* x16    = (unsigned short*)(ws);
    unsigned short* Wqkv16 = (unsigned short*)(ws + 8388608);
    unsigned short* Wo16   = (unsigned short*)(ws + 14680064);
    float* biasqkv         = (float*)(ws + 16777216);
    float* ropeC           = (float*)(ws + 16793600);
    float* ropeS           = (float*)(ws + 17055744);
    unsigned short* QKVw   = (unsigned short*)(ws + 17825792);
    unsigned short* Yw     = (unsigned short*)(ws + 42991616);

    prep_kernel<<<dim3(2048), dim3(256), 0, stream>>>(x, Wq, Wk, Wv, Wo, bq, bk, bv,
                                                x16, Wqkv16, Wo16, biasqkv, ropeC, ropeS);
    qkv_gemm_kernel<<<dim3(768), dim3(512), 0, stream>>>(x16, Wqkv16, biasqkv, ropeC, ropeS, QKVw);
    attn_mfma_kernel<<<dim3(512), dim3(512), 0, stream>>>(QKVw, ropeC, ropeS, Yw);
    out_gemm_kernel<<<dim3(256), dim3(512), 0, stream>>>(Yw, Wo16, bo, out);
}